// Round 1
// baseline (426.797 us; speedup 1.0000x reference)
//
#include <hip/hip_runtime.h>

#define NT 256
#define NL 4

constexpr int Lc   = 2048;
constexpr int Mc   = 21;
constexpr int WIN  = 10;
constexpr int H2c  = 42;                 // 2*M
constexpr int GROUPS = Lc / (NT * NL);   // 2

__global__ __launch_bounds__(NT) void frac_fused(
    const float* __restrict__ x,
    const float* __restrict__ orders,
    const float* __restrict__ ln_w,
    const float* __restrict__ ln_b,
    const float* __restrict__ w1,
    const float* __restrict__ b1,
    const float* __restrict__ w2,
    const float* __restrict__ b2,
    float* __restrict__ out)
{
    __shared__ __align__(16) float xs[WIN - 1 + Lc + 4];   // 9-zero front pad + x + tail pad
    __shared__ __align__(16) float Wc[Mc][12];             // fracdiff coefs, padded row
    __shared__ __align__(16) float w1s[H2c][24];           // (42,21) padded row
    __shared__ float b1s[H2c];
    __shared__ float wbars[H2c];
    __shared__ float redbuf[2][NT / 64];
    __shared__ float sstat[3];                             // mu, rstd, bbar

    const int bc  = blockIdx.x;
    const int tid = threadIdx.x;
    const float* xg = x + (size_t)bc * Lc;

    // ---- stage x into LDS with causal zero pad ----
    for (int i = tid; i < Lc; i += NT) xs[WIN - 1 + i] = xg[i];
    if (tid < WIN - 1) xs[tid] = 0.f;
    if (tid < 4) xs[WIN - 1 + Lc + tid] = 0.f;

    // ---- fracdiff coefficients: c0=1, ck = c(k-1)*(k-1-n)/k ----
    if (tid < Mc) {
        float n = orders[tid];
        float c = 1.f;
        Wc[tid][0] = 1.f;
        #pragma unroll
        for (int k = 1; k < WIN; ++k) {
            c *= ((float)(k - 1) - n) / (float)k;
            Wc[tid][k] = c;
        }
        Wc[tid][10] = 0.f;
        Wc[tid][11] = 0.f;
    }
    // ---- MLP weights into LDS ----
    for (int i = tid; i < H2c * 24; i += NT) {
        int h = i / 24, m = i - h * 24;
        w1s[h][m] = (m < Mc) ? w1[h * Mc + m] : 0.f;
    }
    if (tid < H2c) {
        b1s[tid] = b1[tid];
        float s = 0.f;
        for (int m = 0; m < Mc; ++m) s += w2[m * H2c + tid];
        wbars[tid] = s * (1.f / (float)Mc);    // mean_m w2[m,h]
    }
    if (tid == 0) {
        float s = 0.f;
        for (int m = 0; m < Mc; ++m) s += b2[m];
        sstat[2] = s * (1.f / (float)Mc);      // mean(b2)
    }
    __syncthreads();

    // ---- pass 1: sum / sumsq of diffs over (L, M) ----
    float s1 = 0.f, s2 = 0.f;
    #pragma unroll 1
    for (int g = 0; g < GROUPS; ++g) {
        const int l0 = (g * NT + tid) * NL;
        float xw[16];
        #pragma unroll
        for (int j = 0; j < 4; ++j) {
            float4 v = *reinterpret_cast<const float4*>(&xs[l0 + 4 * j]);
            xw[4*j+0] = v.x; xw[4*j+1] = v.y; xw[4*j+2] = v.z; xw[4*j+3] = v.w;
        }
        #pragma unroll 1
        for (int m = 0; m < Mc; ++m) {
            float w[12];
            #pragma unroll
            for (int j = 0; j < 3; ++j) {
                float4 v = *reinterpret_cast<const float4*>(&Wc[m][4 * j]);
                w[4*j+0] = v.x; w[4*j+1] = v.y; w[4*j+2] = v.z; w[4*j+3] = v.w;
            }
            #pragma unroll
            for (int il = 0; il < NL; ++il) {
                float d = 0.f;
                #pragma unroll
                for (int k = 0; k < WIN; ++k) d = fmaf(w[k], xw[9 + il - k], d);
                s1 += d;
                s2 = fmaf(d, d, s2);
            }
        }
    }
    #pragma unroll
    for (int off = 32; off >= 1; off >>= 1) {
        s1 += __shfl_down(s1, off);
        s2 += __shfl_down(s2, off);
    }
    if ((tid & 63) == 0) {
        redbuf[0][tid >> 6] = s1;
        redbuf[1][tid >> 6] = s2;
    }
    __syncthreads();
    if (tid == 0) {
        float a = 0.f, b = 0.f;
        #pragma unroll
        for (int w = 0; w < NT / 64; ++w) { a += redbuf[0][w]; b += redbuf[1][w]; }
        const float invN = 1.f / (float)(Lc * Mc);
        float mu  = a * invN;
        float var = b * invN - mu * mu;
        sstat[0] = mu;
        sstat[1] = rsqrtf(var + 1e-6f);
    }
    __syncthreads();
    const float mu = sstat[0], rstd = sstat[1], bbar = sstat[2];

    // ---- pass 2: recompute conv, normalize, MLP, reduce, residual ----
    #pragma unroll 1
    for (int g = 0; g < GROUPS; ++g) {
        const int l0 = (g * NT + tid) * NL;
        float xw[16];
        #pragma unroll
        for (int j = 0; j < 4; ++j) {
            float4 v = *reinterpret_cast<const float4*>(&xs[l0 + 4 * j]);
            xw[4*j+0] = v.x; xw[4*j+1] = v.y; xw[4*j+2] = v.z; xw[4*j+3] = v.w;
        }
        float hn[NL][Mc];
        #pragma unroll
        for (int m = 0; m < Mc; ++m) {     // fully unrolled: hn index must be static
            float w[12];
            #pragma unroll
            for (int j = 0; j < 3; ++j) {
                float4 v = *reinterpret_cast<const float4*>(&Wc[m][4 * j]);
                w[4*j+0] = v.x; w[4*j+1] = v.y; w[4*j+2] = v.z; w[4*j+3] = v.w;
            }
            #pragma unroll
            for (int il = 0; il < NL; ++il) {
                float d = 0.f;
                #pragma unroll
                for (int k = 0; k < WIN; ++k) d = fmaf(w[k], xw[9 + il - k], d);
                hn[il][m] = (d - mu) * rstd;
            }
        }
        // LayerNorm affine (ln_w, ln_b are per (l,m))
        #pragma unroll
        for (int il = 0; il < NL; ++il) {
            const float* lw = ln_w + (size_t)(l0 + il) * Mc;
            const float* lb = ln_b + (size_t)(l0 + il) * Mc;
            #pragma unroll
            for (int m = 0; m < Mc; ++m)
                hn[il][m] = fmaf(hn[il][m], lw[m], lb[m]);
        }
        // MLP: t = w1 @ hn + b1; g = gelu(t); acc = sum_h g[h]*wbar[h]
        float acc[NL] = {0.f, 0.f, 0.f, 0.f};
        #pragma unroll 1
        for (int h = 0; h < H2c; ++h) {
            float wr[24];
            #pragma unroll
            for (int j = 0; j < 6; ++j) {
                float4 v = *reinterpret_cast<const float4*>(&w1s[h][4 * j]);
                wr[4*j+0] = v.x; wr[4*j+1] = v.y; wr[4*j+2] = v.z; wr[4*j+3] = v.w;
            }
            const float bh = b1s[h], wbh = wbars[h];
            #pragma unroll
            for (int il = 0; il < NL; ++il) {
                float tt = bh;
                #pragma unroll
                for (int m = 0; m < Mc; ++m) tt = fmaf(wr[m], hn[il][m], tt);
                float ge = 0.5f * tt * (1.f + erff(tt * 0.70710678118654752f));
                acc[il] = fmaf(ge, wbh, acc[il]);
            }
        }
        float4 o;
        o.x = xs[WIN - 1 + l0 + 0] + acc[0] + bbar;
        o.y = xs[WIN - 1 + l0 + 1] + acc[1] + bbar;
        o.z = xs[WIN - 1 + l0 + 2] + acc[2] + bbar;
        o.w = xs[WIN - 1 + l0 + 3] + acc[3] + bbar;
        *reinterpret_cast<float4*>(&out[(size_t)bc * Lc + l0]) = o;
    }
}

extern "C" void kernel_launch(void* const* d_in, const int* in_sizes, int n_in,
                              void* d_out, int out_size, void* d_ws, size_t ws_size,
                              hipStream_t stream) {
    const float* x      = (const float*)d_in[0];
    const float* orders = (const float*)d_in[1];
    const float* ln_w   = (const float*)d_in[2];
    const float* ln_b   = (const float*)d_in[3];
    const float* w1     = (const float*)d_in[4];
    const float* b1     = (const float*)d_in[5];
    const float* w2     = (const float*)d_in[6];
    const float* b2     = (const float*)d_in[7];
    float* out = (float*)d_out;

    const int nbc = in_sizes[0] / Lc;   // B*C = 1472
    frac_fused<<<nbc, NT, 0, stream>>>(x, orders, ln_w, ln_b, w1, b1, w2, b2, out);
}

// Round 3
// 143.671 us; speedup vs baseline: 2.9707x; 2.9707x over previous
//
#include <hip/hip_runtime.h>
#include <cstdint>
#include <cstddef>

typedef _Float16 h2 __attribute__((ext_vector_type(2)));
typedef __fp16  h2fp __attribute__((ext_vector_type(2)));

#define NT 256
constexpr int Lc   = 2048;
constexpr int Mc   = 21;
constexpr int WIN  = 10;
constexpr int H2c  = 42;
constexpr int NL   = 4;
constexpr int GROUPS = Lc / (NT * NL);   // 2
constexpr int XPAD  = 2080;              // 9 front zeros + 2048 + tail zeros
constexpr int NPAIR = Lc / 2 + 8;        // 1032

__device__ __forceinline__ h2 pkh(float a, float b) {
#if __has_builtin(__builtin_amdgcn_cvt_pkrtz)
    h2fp r = __builtin_amdgcn_cvt_pkrtz(a, b);
    return __builtin_bit_cast(h2, r);
#else
    h2 r; r[0] = (_Float16)a; r[1] = (_Float16)b; return r;
#endif
}
__device__ __forceinline__ float fdot2f(h2 a, h2 b, float c) {
#if __has_builtin(__builtin_amdgcn_fdot2)
    return __builtin_amdgcn_fdot2(a, b, c, false);
#else
    return c + (float)a[0] * (float)b[0] + (float)a[1] * (float)b[1];
#endif
}
__device__ __forceinline__ float fast_exp2(float x) {
#if __has_builtin(__builtin_amdgcn_exp2f)
    return __builtin_amdgcn_exp2f(x);
#else
    return exp2f(x);
#endif
}
__device__ __forceinline__ float fast_rcp(float x) {
#if __has_builtin(__builtin_amdgcn_rcpf)
    return __builtin_amdgcn_rcpf(x);
#else
    return 1.f / x;
#endif
}
__device__ __forceinline__ float gelu_f(float t) {
    // gelu(t) ~= t * sigmoid(2u), u = 0.7978845608*(t + 0.044715 t^3)
    const float C0z = 0.79788456080286536f * 2.8853900817779268f;  // 2u*log2(e) linear coef
    const float C1z = 0.035677408136300125f * 2.8853900817779268f; // cubic coef
    float t2 = t * t;
    float z  = t * fmaf(C1z, t2, C0z);
    float v  = fast_exp2(z);           // e^{2u}
    float r  = fast_rcp(1.f + v);
    return fmaf(-t, r, t);             // t*(1 - 1/(1+e^{2u}))
}
__device__ __forceinline__ h2 bch2(float x)   { return __builtin_bit_cast(h2, x); }
__device__ __forceinline__ h2 bch2u(unsigned x){ return __builtin_bit_cast(h2, x); }
__device__ __forceinline__ unsigned bcu(h2 x) { return __builtin_bit_cast(unsigned, x); }

// repack ln_w/ln_b (L,21) f32 -> per (l, mp): uint2{ half2(lw[2mp],lw[2mp+1]), half2(lb...) }
__global__ __launch_bounds__(256) void repack_ln(const float* __restrict__ lnw,
                                                 const float* __restrict__ lnb,
                                                 uint2* __restrict__ dst) {
    int i = blockIdx.x * 256 + threadIdx.x;
    if (i >= Lc * 12) return;
    int l = i / 12, j = i - 12 * l;
    int m0 = 2 * j, m1 = 2 * j + 1;
    float w0 = (m0 < Mc) ? lnw[l * Mc + m0] : 0.f;
    float w1v = (m1 < Mc) ? lnw[l * Mc + m1] : 0.f;
    float b0 = (m0 < Mc) ? lnb[l * Mc + m0] : 0.f;
    float b1v = (m1 < Mc) ? lnb[l * Mc + m1] : 0.f;
    uint2 o; o.x = bcu(pkh(w0, w1v)); o.y = bcu(pkh(b0, b1v));
    dst[i] = o;
}

template<bool PACKED>
__global__ __launch_bounds__(NT, 4) void frac2(
    const float* __restrict__ x, const float* __restrict__ orders,
    const float* __restrict__ ln_w, const float* __restrict__ ln_b,
    const float* __restrict__ w1, const float* __restrict__ b1,
    const float* __restrict__ w2, const float* __restrict__ b2,
    const uint2* __restrict__ lnpk,
    float* __restrict__ out)
{
    __shared__ __align__(16) float xs[XPAD];
    __shared__ __align__(16) h2 xhe[NPAIR];      // (xp[2t], xp[2t+1])
    __shared__ __align__(16) h2 xho[NPAIR];      // (xp[2t+1], xp[2t+2])
    __shared__ __align__(16) float Wc[Mc][12];   // f32 coefs (stats)
    __shared__ __align__(16) h2 Wh[Mc + 1][8];   // conv pairs: [q] = (W[2q+1], W[2q]); row 21 = 0
    __shared__ __align__(16) h2 w1h[H2c][12];    // (w1[h,2j], w1[h,2j+1])
    __shared__ __align__(16) float2 bw[H2c];     // (b1[h], wbar[h])
    __shared__ float partial[NT / 64][11];
    __shared__ float Rs[11];                     // R(0..9), [10] = Sx
    __shared__ float Ey[WIN];
    __shared__ float Gt[WIN][WIN];
    __shared__ float sm1[Mc], sm2[Mc];
    __shared__ float sstat[4];                   // mu, rstd, bbar

    const int bc = blockIdx.x, tid = threadIdx.x;
    const float* xg = x + (size_t)bc * Lc;

    // ---- stage x (padded) ----
    for (int i = tid; i < Lc / 4; i += NT) {
        float4 v = reinterpret_cast<const float4*>(xg)[i];
        xs[9 + 4 * i + 0] = v.x; xs[9 + 4 * i + 1] = v.y;
        xs[9 + 4 * i + 2] = v.z; xs[9 + 4 * i + 3] = v.w;
    }
    if (tid < 9) xs[tid] = 0.f;
    for (int i = Lc + 9 + tid; i < XPAD; i += NT) xs[i] = 0.f;

    // ---- coefficients / weights (independent of xs) ----
    if (tid < Mc) {
        float n = orders[tid], c = 1.f;
        float wk[WIN]; wk[0] = 1.f;
        Wc[tid][0] = 1.f;
        #pragma unroll
        for (int k = 1; k < WIN; ++k) { c *= ((float)(k - 1) - n) / (float)k; Wc[tid][k] = c; wk[k] = c; }
        Wc[tid][10] = 0.f; Wc[tid][11] = 0.f;
        #pragma unroll
        for (int q = 0; q < 5; ++q) Wh[tid][q] = pkh(wk[2 * q + 1], wk[2 * q]);
        #pragma unroll
        for (int q = 5; q < 8; ++q) Wh[tid][q] = pkh(0.f, 0.f);
    }
    if (tid == Mc) {
        #pragma unroll
        for (int q = 0; q < 8; ++q) Wh[Mc][q] = pkh(0.f, 0.f);
    }
    for (int i = tid; i < H2c * 12; i += NT) {
        int h = i / 12, j = i - 12 * h;
        int m0 = 2 * j, m1 = 2 * j + 1;
        float v0 = (m0 < Mc) ? w1[h * Mc + m0] : 0.f;
        float v1 = (m1 < Mc) ? w1[h * Mc + m1] : 0.f;
        w1h[h][j] = pkh(v0, v1);
    }
    if (tid < H2c) {
        float s = 0.f;
        for (int m = 0; m < Mc; ++m) s += w2[m * H2c + tid];
        float2 t; t.x = b1[tid]; t.y = s * (1.f / (float)Mc);
        bw[tid] = t;
    }
    if (tid == NT - 1) {
        float s = 0.f;
        for (int m = 0; m < Mc; ++m) s += b2[m];
        sstat[2] = s * (1.f / (float)Mc);
    }
    __syncthreads();   // B0: xs ready

    // ---- build f16 pair images of xp ----
    for (int t = tid; t < NPAIR; t += NT) {
        xhe[t] = pkh(xs[2 * t], xs[2 * t + 1]);
        xho[t] = pkh(xs[2 * t + 1], xs[2 * t + 2]);
    }

    // ---- autocorrelation partials: R(d)=sum_t x[t]x[t+d], Sx ----
    float Rp[11];
    #pragma unroll
    for (int d = 0; d < 11; ++d) Rp[d] = 0.f;
    #pragma unroll 1
    for (int g = 0; g < GROUPS; ++g) {
        const int l0 = (g * NT + tid) * NL;
        float xw[16];
        #pragma unroll
        for (int j = 0; j < 4; ++j) {
            float4 v = *reinterpret_cast<const float4*>(&xs[8 + l0 + 4 * j]);
            xw[4 * j] = v.x; xw[4 * j + 1] = v.y; xw[4 * j + 2] = v.z; xw[4 * j + 3] = v.w;
        }
        #pragma unroll
        for (int j = 0; j < 4; ++j) {
            Rp[10] += xw[1 + j];
            #pragma unroll
            for (int d = 0; d < 10; ++d) Rp[d] = fmaf(xw[1 + j], xw[1 + j + d], Rp[d]);
        }
    }
    #pragma unroll
    for (int d = 0; d < 11; ++d) {
        float v = Rp[d];
        #pragma unroll
        for (int off = 32; off >= 1; off >>= 1) v += __shfl_xor(v, off);
        if ((tid & 63) == 0) partial[tid >> 6][d] = v;
    }
    __syncthreads();   // B1
    if (tid < 11)
        Rs[tid] = partial[0][tid] + partial[1][tid] + partial[2][tid] + partial[3][tid];
    if (tid == 64) {   // E[k] = sum of last k x's
        float e = 0.f; Ey[0] = 0.f;
        #pragma unroll
        for (int k = 1; k < WIN; ++k) { e += xs[9 + Lc - k]; Ey[k] = e; }
    }
    __syncthreads();   // B2
    if (tid < 100) {   // G(k,k') = R(|k-k'|) - edge correction
        int k = tid / 10, kp = tid - 10 * k;
        int dl = k > kp ? k - kp : kp - k;
        int mx = k > kp ? k : kp;
        float Bsum = 0.f;
        for (int t = Lc - mx; t <= Lc - 1 - dl; ++t) Bsum += xs[9 + t] * xs[9 + t + dl];
        Gt[k][kp] = Rs[dl] - Bsum;
    }
    __syncthreads();   // B3
    if (tid < Mc) {
        const float Sx = Rs[10];
        float s1 = 0.f, s2 = 0.f;
        #pragma unroll
        for (int k = 0; k < WIN; ++k) {
            s1 = fmaf(Wc[tid][k], Sx - Ey[k], s1);
            float inner = 0.f;
            #pragma unroll
            for (int kp = 0; kp < WIN; ++kp) inner = fmaf(Wc[tid][kp], Gt[k][kp], inner);
            s2 = fmaf(Wc[tid][k], inner, s2);
        }
        sm1[tid] = s1; sm2[tid] = s2;
    }
    __syncthreads();   // B4
    if (tid == 0) {
        float a = 0.f, b = 0.f;
        for (int m = 0; m < Mc; ++m) { a += sm1[m]; b += sm2[m]; }
        const float invN = 1.f / (float)(Lc * Mc);
        float muv = a * invN;
        float msv = b * invN;
        sstat[0] = muv;
        sstat[1] = rsqrtf(msv - muv * muv + 1e-6f);
    }
    __syncthreads();   // B5
    const float mu = sstat[0], rstd = sstat[1], bbar = sstat[2];
    h2 rs2; rs2[0] = (_Float16)rstd;  rs2[1] = (_Float16)rstd;
    h2 nm2; nm2[0] = (_Float16)(-mu); nm2[1] = (_Float16)(-mu);

    // ---- main pass: conv (fdot2) -> LN affine -> MLP -> residual ----
    #pragma unroll 1
    for (int g = 0; g < GROUPS; ++g) {
        const int l0 = (g * NT + tid) * NL;
        const int t0 = l0 >> 1;   // even
        h2 ue0, ue1, ue2, ue3, ue4, ue5, uo0, uo1, uo2, uo3, uo4, uo5;
        {
            float2 p0 = *reinterpret_cast<const float2*>(&xhe[t0]);
            float2 p1 = *reinterpret_cast<const float2*>(&xhe[t0 + 2]);
            float2 p2 = *reinterpret_cast<const float2*>(&xhe[t0 + 4]);
            ue0 = bch2(p0.x); ue1 = bch2(p0.y); ue2 = bch2(p1.x);
            ue3 = bch2(p1.y); ue4 = bch2(p2.x); ue5 = bch2(p2.y);
            float2 q0 = *reinterpret_cast<const float2*>(&xho[t0]);
            float2 q1 = *reinterpret_cast<const float2*>(&xho[t0 + 2]);
            float2 q2 = *reinterpret_cast<const float2*>(&xho[t0 + 4]);
            uo0 = bch2(q0.x); uo1 = bch2(q0.y); uo2 = bch2(q1.x);
            uo3 = bch2(q1.y); uo4 = bch2(q2.x); uo5 = bch2(q2.y);
        }
        h2 hnp[NL][11];
        const uint2* lnrow = PACKED ? (lnpk + (size_t)l0 * 12) : nullptr;
        const float* lwr = ln_w + (size_t)l0 * Mc;
        const float* lbr = ln_b + (size_t)l0 * Mc;
        #pragma unroll
        for (int mp = 0; mp < 11; ++mp) {
            const int m0 = 2 * mp;
            const int m1 = (mp < 10) ? (2 * mp + 1) : Mc;   // row Mc is zeros
            float4 wa = *reinterpret_cast<const float4*>(&Wh[m0][0]);
            h2 wa0 = bch2(wa.x), wa1 = bch2(wa.y), wa2 = bch2(wa.z), wa3 = bch2(wa.w);
            h2 wa4 = Wh[m0][4];
            float4 wb = *reinterpret_cast<const float4*>(&Wh[m1][0]);
            h2 wb0 = bch2(wb.x), wb1 = bch2(wb.y), wb2 = bch2(wb.z), wb3 = bch2(wb.w);
            h2 wb4 = Wh[m1][4];
            // conv: d[l0+il] for m0 and m1
            float d00 = fdot2f(ue0, wa4, fdot2f(ue1, wa3, fdot2f(ue2, wa2, fdot2f(ue3, wa1, fdot2f(ue4, wa0, 0.f)))));
            float d01 = fdot2f(uo0, wa4, fdot2f(uo1, wa3, fdot2f(uo2, wa2, fdot2f(uo3, wa1, fdot2f(uo4, wa0, 0.f)))));
            float d02 = fdot2f(ue1, wa4, fdot2f(ue2, wa3, fdot2f(ue3, wa2, fdot2f(ue4, wa1, fdot2f(ue5, wa0, 0.f)))));
            float d03 = fdot2f(uo1, wa4, fdot2f(uo2, wa3, fdot2f(uo3, wa2, fdot2f(uo4, wa1, fdot2f(uo5, wa0, 0.f)))));
            float d10 = fdot2f(ue0, wb4, fdot2f(ue1, wb3, fdot2f(ue2, wb2, fdot2f(ue3, wb1, fdot2f(ue4, wb0, 0.f)))));
            float d11 = fdot2f(uo0, wb4, fdot2f(uo1, wb3, fdot2f(uo2, wb2, fdot2f(uo3, wb1, fdot2f(uo4, wb0, 0.f)))));
            float d12 = fdot2f(ue1, wb4, fdot2f(ue2, wb3, fdot2f(ue3, wb2, fdot2f(ue4, wb1, fdot2f(ue5, wb0, 0.f)))));
            float d13 = fdot2f(uo1, wb4, fdot2f(uo2, wb3, fdot2f(uo3, wb2, fdot2f(uo4, wb1, fdot2f(uo5, wb0, 0.f)))));
            if constexpr (PACKED) {
                uint2 lp0 = lnrow[0 * 12 + mp];
                uint2 lp1 = lnrow[1 * 12 + mp];
                uint2 lp2 = lnrow[2 * 12 + mp];
                uint2 lp3 = lnrow[3 * 12 + mp];
                { h2 aw = bch2u(lp0.x) * rs2; h2 bh = aw * nm2 + bch2u(lp0.y); hnp[0][mp] = pkh(d00, d10) * aw + bh; }
                { h2 aw = bch2u(lp1.x) * rs2; h2 bh = aw * nm2 + bch2u(lp1.y); hnp[1][mp] = pkh(d01, d11) * aw + bh; }
                { h2 aw = bch2u(lp2.x) * rs2; h2 bh = aw * nm2 + bch2u(lp2.y); hnp[2][mp] = pkh(d02, d12) * aw + bh; }
                { h2 aw = bch2u(lp3.x) * rs2; h2 bh = aw * nm2 + bch2u(lp3.y); hnp[3][mp] = pkh(d03, d13) * aw + bh; }
            } else {
                #define AFFINE(IL, DA, DB)                                                   \
                {                                                                            \
                    float lw0 = lwr[(IL) * Mc + m0];                                         \
                    float lb0 = lbr[(IL) * Mc + m0];                                         \
                    float lw1 = (mp < 10) ? lwr[(IL) * Mc + m0 + 1] : 0.f;                   \
                    float lb1 = (mp < 10) ? lbr[(IL) * Mc + m0 + 1] : 0.f;                   \
                    float a0 = rstd * lw0, a1 = rstd * lw1;                                  \
                    float h0 = fmaf(DA - mu, a0, lb0);                                       \
                    float h1 = fmaf(DB - mu, a1, lb1);                                       \
                    hnp[IL][mp] = pkh(h0, h1);                                               \
                }
                AFFINE(0, d00, d10) AFFINE(1, d01, d11) AFFINE(2, d02, d12) AFFINE(3, d03, d13)
                #undef AFFINE
            }
        }
        // MLP + gelu + folded second GEMM
        float acc0 = 0.f, acc1 = 0.f, acc2 = 0.f, acc3 = 0.f;
        #pragma unroll 1
        for (int h = 0; h < H2c; ++h) {
            float4 a = *reinterpret_cast<const float4*>(&w1h[h][0]);
            float4 b4 = *reinterpret_cast<const float4*>(&w1h[h][4]);
            float4 c4 = *reinterpret_cast<const float4*>(&w1h[h][8]);
            h2 wj0 = bch2(a.x), wj1 = bch2(a.y), wj2 = bch2(a.z), wj3 = bch2(a.w);
            h2 wj4 = bch2(b4.x), wj5 = bch2(b4.y), wj6 = bch2(b4.z), wj7 = bch2(b4.w);
            h2 wj8 = bch2(c4.x), wj9 = bch2(c4.y), wj10 = bch2(c4.z);
            float2 bwv = bw[h];
            #define DOT11(TI, IL)                                                            \
                float TI = bwv.x;                                                            \
                TI = fdot2f(hnp[IL][0], wj0, TI);  TI = fdot2f(hnp[IL][1], wj1, TI);         \
                TI = fdot2f(hnp[IL][2], wj2, TI);  TI = fdot2f(hnp[IL][3], wj3, TI);         \
                TI = fdot2f(hnp[IL][4], wj4, TI);  TI = fdot2f(hnp[IL][5], wj5, TI);         \
                TI = fdot2f(hnp[IL][6], wj6, TI);  TI = fdot2f(hnp[IL][7], wj7, TI);         \
                TI = fdot2f(hnp[IL][8], wj8, TI);  TI = fdot2f(hnp[IL][9], wj9, TI);         \
                TI = fdot2f(hnp[IL][10], wj10, TI);
            DOT11(tv0, 0) DOT11(tv1, 1) DOT11(tv2, 2) DOT11(tv3, 3)
            #undef DOT11
            acc0 = fmaf(gelu_f(tv0), bwv.y, acc0);
            acc1 = fmaf(gelu_f(tv1), bwv.y, acc1);
            acc2 = fmaf(gelu_f(tv2), bwv.y, acc2);
            acc3 = fmaf(gelu_f(tv3), bwv.y, acc3);
        }
        float4 o;
        o.x = xs[9 + l0 + 0] + acc0 + bbar;
        o.y = xs[9 + l0 + 1] + acc1 + bbar;
        o.z = xs[9 + l0 + 2] + acc2 + bbar;
        o.w = xs[9 + l0 + 3] + acc3 + bbar;
        *reinterpret_cast<float4*>(&out[(size_t)bc * Lc + l0]) = o;
    }
}

extern "C" void kernel_launch(void* const* d_in, const int* in_sizes, int n_in,
                              void* d_out, int out_size, void* d_ws, size_t ws_size,
                              hipStream_t stream) {
    const float* x      = (const float*)d_in[0];
    const float* orders = (const float*)d_in[1];
    const float* ln_w   = (const float*)d_in[2];
    const float* ln_b   = (const float*)d_in[3];
    const float* w1     = (const float*)d_in[4];
    const float* b1     = (const float*)d_in[5];
    const float* w2     = (const float*)d_in[6];
    const float* b2     = (const float*)d_in[7];
    float* out = (float*)d_out;

    const int nbc = in_sizes[0] / Lc;   // B*C = 1472
    const size_t need = (size_t)Lc * 12 * sizeof(uint2);
    if (ws_size >= need) {
        repack_ln<<<(Lc * 12 + 255) / 256, 256, 0, stream>>>(ln_w, ln_b, (uint2*)d_ws);
        frac2<true><<<nbc, NT, 0, stream>>>(x, orders, ln_w, ln_b, w1, b1, w2, b2,
                                            (const uint2*)d_ws, out);
    } else {
        frac2<false><<<nbc, NT, 0, stream>>>(x, orders, ln_w, ln_b, w1, b1, w2, b2,
                                             nullptr, out);
    }
}

// Round 4
// 137.739 us; speedup vs baseline: 3.0986x; 1.0431x over previous
//
#include <hip/hip_runtime.h>
#include <cstdint>
#include <cstddef>

typedef _Float16 h2 __attribute__((ext_vector_type(2)));
typedef __fp16  h2fp __attribute__((ext_vector_type(2)));

#define NT 256
constexpr int Lc   = 2048;
constexpr int Mc   = 21;
constexpr int WIN  = 10;
constexpr int H2c  = 42;
constexpr int NL   = 4;
constexpr int GROUPS = Lc / (NT * NL);   // 2
constexpr int XPAD  = 2080;              // 9 front zeros + 2048 + tail zeros
constexpr int NPAIR = Lc / 2 + 8;        // 1032

__device__ __forceinline__ h2 pkh(float a, float b) {
#if __has_builtin(__builtin_amdgcn_cvt_pkrtz)
    h2fp r = __builtin_amdgcn_cvt_pkrtz(a, b);
    return __builtin_bit_cast(h2, r);
#else
    h2 r; r[0] = (_Float16)a; r[1] = (_Float16)b; return r;
#endif
}
__device__ __forceinline__ float fdot2f(h2 a, h2 b, float c) {
#if __has_builtin(__builtin_amdgcn_fdot2)
    return __builtin_amdgcn_fdot2(a, b, c, false);
#else
    return c + (float)a[0] * (float)b[0] + (float)a[1] * (float)b[1];
#endif
}
__device__ __forceinline__ float fast_exp2(float x) {
#if __has_builtin(__builtin_amdgcn_exp2f)
    return __builtin_amdgcn_exp2f(x);
#else
    return exp2f(x);
#endif
}
__device__ __forceinline__ float fast_rcp(float x) {
#if __has_builtin(__builtin_amdgcn_rcpf)
    return __builtin_amdgcn_rcpf(x);
#else
    return 1.f / x;
#endif
}
__device__ __forceinline__ float gelu_f(float t) {
    // gelu(t) ~= t * sigmoid(2u), u = 0.7978845608*(t + 0.044715 t^3)
    const float C0z = 0.79788456080286536f * 2.8853900817779268f;  // 2u*log2(e) linear coef
    const float C1z = 0.035677408136300125f * 2.8853900817779268f; // cubic coef
    float t2 = t * t;
    float z  = t * fmaf(C1z, t2, C0z);
    float v  = fast_exp2(z);           // e^{2u}
    float r  = fast_rcp(1.f + v);
    return fmaf(-t, r, t);             // t*(1 - 1/(1+e^{2u}))
}
__device__ __forceinline__ h2 bch2(float x)   { return __builtin_bit_cast(h2, x); }
__device__ __forceinline__ h2 bch2u(unsigned x){ return __builtin_bit_cast(h2, x); }
__device__ __forceinline__ unsigned bcu(h2 x) { return __builtin_bit_cast(unsigned, x); }

// repack ln_w/ln_b (L,21) f32 -> per (l, mp): uint2{ half2(lw[2mp],lw[2mp+1]), half2(lb...) }
__global__ __launch_bounds__(256) void repack_ln(const float* __restrict__ lnw,
                                                 const float* __restrict__ lnb,
                                                 uint2* __restrict__ dst) {
    int i = blockIdx.x * 256 + threadIdx.x;
    if (i >= Lc * 12) return;
    int l = i / 12, j = i - 12 * l;
    int m0 = 2 * j, m1 = 2 * j + 1;
    float w0 = (m0 < Mc) ? lnw[l * Mc + m0] : 0.f;
    float w1v = (m1 < Mc) ? lnw[l * Mc + m1] : 0.f;
    float b0 = (m0 < Mc) ? lnb[l * Mc + m0] : 0.f;
    float b1v = (m1 < Mc) ? lnb[l * Mc + m1] : 0.f;
    uint2 o; o.x = bcu(pkh(w0, w1v)); o.y = bcu(pkh(b0, b1v));
    dst[i] = o;
}

template<bool PACKED>
__global__ __launch_bounds__(NT) void frac2(
    const float* __restrict__ x, const float* __restrict__ orders,
    const float* __restrict__ ln_w, const float* __restrict__ ln_b,
    const float* __restrict__ w1, const float* __restrict__ b1,
    const float* __restrict__ w2, const float* __restrict__ b2,
    const uint2* __restrict__ lnpk,
    float* __restrict__ out)
{
    __shared__ __align__(16) float xs[XPAD];
    __shared__ __align__(16) h2 xhe[NPAIR];      // (xp[2t], xp[2t+1])
    __shared__ __align__(16) h2 xho[NPAIR];      // (xp[2t+1], xp[2t+2])
    __shared__ __align__(16) float Wc[Mc][12];   // f32 coefs (stats)
    __shared__ __align__(16) h2 Wh[Mc + 1][8];   // conv pairs: [q] = (W[2q+1], W[2q]); row 21 = 0
    __shared__ __align__(16) h2 w1h[H2c][12];    // (w1[h,2j], w1[h,2j+1])
    __shared__ __align__(16) float2 bw[H2c];     // (b1[h], wbar[h])
    __shared__ float partial[NT / 64][11];
    __shared__ float Rs[11];                     // R(0..9), [10] = Sx
    __shared__ float Ey[WIN];
    __shared__ float Gt[WIN][WIN];
    __shared__ float sm1[Mc], sm2[Mc];
    __shared__ float sstat[4];                   // mu, rstd, bbar

    const int bc = blockIdx.x, tid = threadIdx.x;
    const float* xg = x + (size_t)bc * Lc;

    // ---- stage x (padded) ----
    for (int i = tid; i < Lc / 4; i += NT) {
        float4 v = reinterpret_cast<const float4*>(xg)[i];
        xs[9 + 4 * i + 0] = v.x; xs[9 + 4 * i + 1] = v.y;
        xs[9 + 4 * i + 2] = v.z; xs[9 + 4 * i + 3] = v.w;
    }
    if (tid < 9) xs[tid] = 0.f;
    for (int i = Lc + 9 + tid; i < XPAD; i += NT) xs[i] = 0.f;

    // ---- coefficients / weights (independent of xs) ----
    if (tid < Mc) {
        float n = orders[tid], c = 1.f;
        float wk[WIN]; wk[0] = 1.f;
        Wc[tid][0] = 1.f;
        #pragma unroll
        for (int k = 1; k < WIN; ++k) { c *= ((float)(k - 1) - n) / (float)k; Wc[tid][k] = c; wk[k] = c; }
        Wc[tid][10] = 0.f; Wc[tid][11] = 0.f;
        #pragma unroll
        for (int q = 0; q < 5; ++q) Wh[tid][q] = pkh(wk[2 * q + 1], wk[2 * q]);
        #pragma unroll
        for (int q = 5; q < 8; ++q) Wh[tid][q] = pkh(0.f, 0.f);
    }
    if (tid == Mc) {
        #pragma unroll
        for (int q = 0; q < 8; ++q) Wh[Mc][q] = pkh(0.f, 0.f);
    }
    for (int i = tid; i < H2c * 12; i += NT) {
        int h = i / 12, j = i - 12 * h;
        int m0 = 2 * j, m1 = 2 * j + 1;
        float v0 = (m0 < Mc) ? w1[h * Mc + m0] : 0.f;
        float v1 = (m1 < Mc) ? w1[h * Mc + m1] : 0.f;
        w1h[h][j] = pkh(v0, v1);
    }
    if (tid < H2c) {
        float s = 0.f;
        for (int m = 0; m < Mc; ++m) s += w2[m * H2c + tid];
        float2 t; t.x = b1[tid]; t.y = s * (1.f / (float)Mc);
        bw[tid] = t;
    }
    if (tid == NT - 1) {
        float s = 0.f;
        for (int m = 0; m < Mc; ++m) s += b2[m];
        sstat[2] = s * (1.f / (float)Mc);
    }
    __syncthreads();   // B0: xs ready

    // ---- build f16 pair images of xp ----
    for (int t = tid; t < NPAIR; t += NT) {
        xhe[t] = pkh(xs[2 * t], xs[2 * t + 1]);
        xho[t] = pkh(xs[2 * t + 1], xs[2 * t + 2]);
    }

    // ---- autocorrelation partials: R(d)=sum_t x[t]x[t+d], Sx ----
    float Rp[11];
    #pragma unroll
    for (int d = 0; d < 11; ++d) Rp[d] = 0.f;
    #pragma unroll 1
    for (int g = 0; g < GROUPS; ++g) {
        const int l0 = (g * NT + tid) * NL;
        float xw[16];
        #pragma unroll
        for (int j = 0; j < 4; ++j) {
            float4 v = *reinterpret_cast<const float4*>(&xs[8 + l0 + 4 * j]);
            xw[4 * j] = v.x; xw[4 * j + 1] = v.y; xw[4 * j + 2] = v.z; xw[4 * j + 3] = v.w;
        }
        #pragma unroll
        for (int j = 0; j < 4; ++j) {
            Rp[10] += xw[1 + j];
            #pragma unroll
            for (int d = 0; d < 10; ++d) Rp[d] = fmaf(xw[1 + j], xw[1 + j + d], Rp[d]);
        }
    }
    #pragma unroll
    for (int d = 0; d < 11; ++d) {
        float v = Rp[d];
        #pragma unroll
        for (int off = 32; off >= 1; off >>= 1) v += __shfl_xor(v, off);
        if ((tid & 63) == 0) partial[tid >> 6][d] = v;
    }
    __syncthreads();   // B1
    if (tid < 11)
        Rs[tid] = partial[0][tid] + partial[1][tid] + partial[2][tid] + partial[3][tid];
    if (tid == 64) {   // E[k] = sum of last k x's
        float e = 0.f; Ey[0] = 0.f;
        #pragma unroll
        for (int k = 1; k < WIN; ++k) { e += xs[9 + Lc - k]; Ey[k] = e; }
    }
    __syncthreads();   // B2
    if (tid < 100) {   // G(k,k') = R(|k-k'|) - edge correction
        int k = tid / 10, kp = tid - 10 * k;
        int dl = k > kp ? k - kp : kp - k;
        int mx = k > kp ? k : kp;
        float Bsum = 0.f;
        for (int t = Lc - mx; t <= Lc - 1 - dl; ++t) Bsum += xs[9 + t] * xs[9 + t + dl];
        Gt[k][kp] = Rs[dl] - Bsum;
    }
    __syncthreads();   // B3
    if (tid < Mc) {
        const float Sx = Rs[10];
        float s1 = 0.f, s2 = 0.f;
        #pragma unroll
        for (int k = 0; k < WIN; ++k) {
            s1 = fmaf(Wc[tid][k], Sx - Ey[k], s1);
            float inner = 0.f;
            #pragma unroll
            for (int kp = 0; kp < WIN; ++kp) inner = fmaf(Wc[tid][kp], Gt[k][kp], inner);
            s2 = fmaf(Wc[tid][k], inner, s2);
        }
        sm1[tid] = s1; sm2[tid] = s2;
    }
    __syncthreads();   // B4
    if (tid == 0) {
        float a = 0.f, b = 0.f;
        for (int m = 0; m < Mc; ++m) { a += sm1[m]; b += sm2[m]; }
        const float invN = 1.f / (float)(Lc * Mc);
        float muv = a * invN;
        float msv = b * invN;
        sstat[0] = muv;
        sstat[1] = rsqrtf(msv - muv * muv + 1e-6f);
    }
    __syncthreads();   // B5
    const float mu = sstat[0], rstd = sstat[1], bbar = sstat[2];
    h2 rs2; rs2[0] = (_Float16)rstd;  rs2[1] = (_Float16)rstd;
    h2 nm2; nm2[0] = (_Float16)(-mu); nm2[1] = (_Float16)(-mu);

    // ---- main pass: conv (fdot2) -> LN affine -> MLP -> residual ----
    #pragma unroll 1
    for (int g = 0; g < GROUPS; ++g) {
        const int l0 = (g * NT + tid) * NL;
        const int t0 = l0 >> 1;   // even
        h2 ue0, ue1, ue2, ue3, ue4, ue5, uo0, uo1, uo2, uo3, uo4, uo5;
        {
            float2 p0 = *reinterpret_cast<const float2*>(&xhe[t0]);
            float2 p1 = *reinterpret_cast<const float2*>(&xhe[t0 + 2]);
            float2 p2 = *reinterpret_cast<const float2*>(&xhe[t0 + 4]);
            ue0 = bch2(p0.x); ue1 = bch2(p0.y); ue2 = bch2(p1.x);
            ue3 = bch2(p1.y); ue4 = bch2(p2.x); ue5 = bch2(p2.y);
            float2 q0 = *reinterpret_cast<const float2*>(&xho[t0]);
            float2 q1 = *reinterpret_cast<const float2*>(&xho[t0 + 2]);
            float2 q2 = *reinterpret_cast<const float2*>(&xho[t0 + 4]);
            uo0 = bch2(q0.x); uo1 = bch2(q0.y); uo2 = bch2(q1.x);
            uo3 = bch2(q1.y); uo4 = bch2(q2.x); uo5 = bch2(q2.y);
        }
        h2 hnp[NL][11];
        const uint2* lnrow = PACKED ? (lnpk + (size_t)l0 * 12) : nullptr;
        const float* lwr = ln_w + (size_t)l0 * Mc;
        const float* lbr = ln_b + (size_t)l0 * Mc;
        #pragma unroll
        for (int mp = 0; mp < 11; ++mp) {
            const int m0 = 2 * mp;
            const int m1 = (mp < 10) ? (2 * mp + 1) : Mc;   // row Mc is zeros
            float4 wa = *reinterpret_cast<const float4*>(&Wh[m0][0]);
            h2 wa0 = bch2(wa.x), wa1 = bch2(wa.y), wa2 = bch2(wa.z), wa3 = bch2(wa.w);
            h2 wa4 = Wh[m0][4];
            float4 wb = *reinterpret_cast<const float4*>(&Wh[m1][0]);
            h2 wb0 = bch2(wb.x), wb1 = bch2(wb.y), wb2 = bch2(wb.z), wb3 = bch2(wb.w);
            h2 wb4 = Wh[m1][4];
            // conv: d[l0+il] for m0 and m1
            float d00 = fdot2f(ue0, wa4, fdot2f(ue1, wa3, fdot2f(ue2, wa2, fdot2f(ue3, wa1, fdot2f(ue4, wa0, 0.f)))));
            float d01 = fdot2f(uo0, wa4, fdot2f(uo1, wa3, fdot2f(uo2, wa2, fdot2f(uo3, wa1, fdot2f(uo4, wa0, 0.f)))));
            float d02 = fdot2f(ue1, wa4, fdot2f(ue2, wa3, fdot2f(ue3, wa2, fdot2f(ue4, wa1, fdot2f(ue5, wa0, 0.f)))));
            float d03 = fdot2f(uo1, wa4, fdot2f(uo2, wa3, fdot2f(uo3, wa2, fdot2f(uo4, wa1, fdot2f(uo5, wa0, 0.f)))));
            float d10 = fdot2f(ue0, wb4, fdot2f(ue1, wb3, fdot2f(ue2, wb2, fdot2f(ue3, wb1, fdot2f(ue4, wb0, 0.f)))));
            float d11 = fdot2f(uo0, wb4, fdot2f(uo1, wb3, fdot2f(uo2, wb2, fdot2f(uo3, wb1, fdot2f(uo4, wb0, 0.f)))));
            float d12 = fdot2f(ue1, wb4, fdot2f(ue2, wb3, fdot2f(ue3, wb2, fdot2f(ue4, wb1, fdot2f(ue5, wb0, 0.f)))));
            float d13 = fdot2f(uo1, wb4, fdot2f(uo2, wb3, fdot2f(uo3, wb2, fdot2f(uo4, wb1, fdot2f(uo5, wb0, 0.f)))));
            if constexpr (PACKED) {
                uint2 lp0 = lnrow[0 * 12 + mp];
                uint2 lp1 = lnrow[1 * 12 + mp];
                uint2 lp2 = lnrow[2 * 12 + mp];
                uint2 lp3 = lnrow[3 * 12 + mp];
                { h2 aw = bch2u(lp0.x) * rs2; h2 bh = aw * nm2 + bch2u(lp0.y); hnp[0][mp] = pkh(d00, d10) * aw + bh; }
                { h2 aw = bch2u(lp1.x) * rs2; h2 bh = aw * nm2 + bch2u(lp1.y); hnp[1][mp] = pkh(d01, d11) * aw + bh; }
                { h2 aw = bch2u(lp2.x) * rs2; h2 bh = aw * nm2 + bch2u(lp2.y); hnp[2][mp] = pkh(d02, d12) * aw + bh; }
                { h2 aw = bch2u(lp3.x) * rs2; h2 bh = aw * nm2 + bch2u(lp3.y); hnp[3][mp] = pkh(d03, d13) * aw + bh; }
            } else {
                #define AFFINE(IL, DA, DB)                                                   \
                {                                                                            \
                    float lw0 = lwr[(IL) * Mc + m0];                                         \
                    float lb0 = lbr[(IL) * Mc + m0];                                         \
                    float lw1 = (mp < 10) ? lwr[(IL) * Mc + m0 + 1] : 0.f;                   \
                    float lb1 = (mp < 10) ? lbr[(IL) * Mc + m0 + 1] : 0.f;                   \
                    float a0 = rstd * lw0, a1 = rstd * lw1;                                  \
                    float h0 = fmaf(DA - mu, a0, lb0);                                       \
                    float h1 = fmaf(DB - mu, a1, lb1);                                       \
                    hnp[IL][mp] = pkh(h0, h1);                                               \
                }
                AFFINE(0, d00, d10) AFFINE(1, d01, d11) AFFINE(2, d02, d12) AFFINE(3, d03, d13)
                #undef AFFINE
            }
        }
        // MLP + gelu + folded second GEMM
        float acc0 = 0.f, acc1 = 0.f, acc2 = 0.f, acc3 = 0.f;
        #pragma unroll 1
        for (int h = 0; h < H2c; ++h) {
            float4 a = *reinterpret_cast<const float4*>(&w1h[h][0]);
            float4 b4 = *reinterpret_cast<const float4*>(&w1h[h][4]);
            float4 c4 = *reinterpret_cast<const float4*>(&w1h[h][8]);
            h2 wj0 = bch2(a.x), wj1 = bch2(a.y), wj2 = bch2(a.z), wj3 = bch2(a.w);
            h2 wj4 = bch2(b4.x), wj5 = bch2(b4.y), wj6 = bch2(b4.z), wj7 = bch2(b4.w);
            h2 wj8 = bch2(c4.x), wj9 = bch2(c4.y), wj10 = bch2(c4.z);
            float2 bwv = bw[h];
            #define DOT11(TI, IL)                                                            \
                float TI = bwv.x;                                                            \
                TI = fdot2f(hnp[IL][0], wj0, TI);  TI = fdot2f(hnp[IL][1], wj1, TI);         \
                TI = fdot2f(hnp[IL][2], wj2, TI);  TI = fdot2f(hnp[IL][3], wj3, TI);         \
                TI = fdot2f(hnp[IL][4], wj4, TI);  TI = fdot2f(hnp[IL][5], wj5, TI);         \
                TI = fdot2f(hnp[IL][6], wj6, TI);  TI = fdot2f(hnp[IL][7], wj7, TI);         \
                TI = fdot2f(hnp[IL][8], wj8, TI);  TI = fdot2f(hnp[IL][9], wj9, TI);         \
                TI = fdot2f(hnp[IL][10], wj10, TI);
            DOT11(tv0, 0) DOT11(tv1, 1) DOT11(tv2, 2) DOT11(tv3, 3)
            #undef DOT11
            acc0 = fmaf(gelu_f(tv0), bwv.y, acc0);
            acc1 = fmaf(gelu_f(tv1), bwv.y, acc1);
            acc2 = fmaf(gelu_f(tv2), bwv.y, acc2);
            acc3 = fmaf(gelu_f(tv3), bwv.y, acc3);
        }
        float4 o;
        o.x = xs[9 + l0 + 0] + acc0 + bbar;
        o.y = xs[9 + l0 + 1] + acc1 + bbar;
        o.z = xs[9 + l0 + 2] + acc2 + bbar;
        o.w = xs[9 + l0 + 3] + acc3 + bbar;
        *reinterpret_cast<float4*>(&out[(size_t)bc * Lc + l0]) = o;
    }
}

extern "C" void kernel_launch(void* const* d_in, const int* in_sizes, int n_in,
                              void* d_out, int out_size, void* d_ws, size_t ws_size,
                              hipStream_t stream) {
    const float* x      = (const float*)d_in[0];
    const float* orders = (const float*)d_in[1];
    const float* ln_w   = (const float*)d_in[2];
    const float* ln_b   = (const float*)d_in[3];
    const float* w1     = (const float*)d_in[4];
    const float* b1     = (const float*)d_in[5];
    const float* w2     = (const float*)d_in[6];
    const float* b2     = (const float*)d_in[7];
    float* out = (float*)d_out;

    const int nbc = in_sizes[0] / Lc;   // B*C = 1472
    const size_t need = (size_t)Lc * 12 * sizeof(uint2);
    if (ws_size >= need) {
        repack_ln<<<(Lc * 12 + 255) / 256, 256, 0, stream>>>(ln_w, ln_b, (uint2*)d_ws);
        frac2<true><<<nbc, NT, 0, stream>>>(x, orders, ln_w, ln_b, w1, b1, w2, b2,
                                            (const uint2*)d_ws, out);
    } else {
        frac2<false><<<nbc, NT, 0, stream>>>(x, orders, ln_w, ln_b, w1, b1, w2, b2,
                                             nullptr, out);
    }
}

// Round 5
// 119.488 us; speedup vs baseline: 3.5719x; 1.1527x over previous
//
#include <hip/hip_runtime.h>
#include <cstdint>
#include <cstddef>

typedef _Float16 h2 __attribute__((ext_vector_type(2)));
typedef __fp16  h2fp __attribute__((ext_vector_type(2)));

#define NT 256
constexpr int Lc   = 2048;
constexpr int Mc   = 21;
constexpr int WIN  = 10;
constexpr int H2c  = 42;
constexpr int NL   = 4;
constexpr int GROUPS = Lc / (NT * NL);   // 2
constexpr int XPAD  = 2080;              // 9 front zeros + 2048 + tail pad
constexpr int NPAIR = Lc / 2 + 8;        // 1032
constexpr int LT    = Lc / 4;            // 512
// ws layout: lnT = 11*512*4 uint2 = 180224 B; bw = 42 float2; bbar = 1 float
constexpr size_t WS_LN_BYTES  = (size_t)11 * LT * 4 * 8;           // 180224
constexpr size_t WS_BW_OFF    = WS_LN_BYTES;
constexpr size_t WS_BBAR_OFF  = WS_BW_OFF + H2c * 8;
constexpr size_t WS_NEED      = WS_BBAR_OFF + 4;

__device__ __forceinline__ h2 pkh(float a, float b) {
#if __has_builtin(__builtin_amdgcn_cvt_pkrtz)
    h2fp r = __builtin_amdgcn_cvt_pkrtz(a, b);
    return __builtin_bit_cast(h2, r);
#else
    h2 r; r[0] = (_Float16)a; r[1] = (_Float16)b; return r;
#endif
}
__device__ __forceinline__ float fdot2f(h2 a, h2 b, float c) {
#if __has_builtin(__builtin_amdgcn_fdot2)
    return __builtin_amdgcn_fdot2(a, b, c, false);
#else
    return c + (float)a[0] * (float)b[0] + (float)a[1] * (float)b[1];
#endif
}
__device__ __forceinline__ float fast_exp2(float x) {
#if __has_builtin(__builtin_amdgcn_exp2f)
    return __builtin_amdgcn_exp2f(x);
#else
    return exp2f(x);
#endif
}
__device__ __forceinline__ float fast_rcp(float x) {
#if __has_builtin(__builtin_amdgcn_rcpf)
    return __builtin_amdgcn_rcpf(x);
#else
    return 1.f / x;
#endif
}
__device__ __forceinline__ float gelu_f(float t) {
    const float C0z = 0.79788456080286536f * 2.8853900817779268f;
    const float C1z = 0.035677408136300125f * 2.8853900817779268f;
    float t2 = t * t;
    float z  = t * fmaf(C1z, t2, C0z);
    float v  = fast_exp2(z);
    float r  = fast_rcp(1.f + v);
    return fmaf(-t, r, t);
}
__device__ __forceinline__ h2 bch2(float x)    { return __builtin_bit_cast(h2, x); }
__device__ __forceinline__ h2 bch2u(unsigned x){ return __builtin_bit_cast(h2, x); }
__device__ __forceinline__ unsigned bcu(h2 x)  { return __builtin_bit_cast(unsigned, x); }

// Pre-kernel: transpose-pack LN params to lane-contiguous layout + fold w2/b2.
// lnT[(mp*512 + lt)*4 + il] = { half2(lw[l,2mp],lw[l,2mp+1]), half2(lb...) }, l = 4*lt+il
__global__ __launch_bounds__(256) void repack_all(
    const float* __restrict__ lnw, const float* __restrict__ lnb,
    const float* __restrict__ w1_, const float* __restrict__ b1,
    const float* __restrict__ w2, const float* __restrict__ b2,
    uint2* __restrict__ lnT, float2* __restrict__ bwT, float* __restrict__ bbarT)
{
    int i = blockIdx.x * 256 + threadIdx.x;
    if (i < Lc * 11) {
        int mp = i / Lc, l = i - mp * Lc;
        int lt = l >> 2, il = l & 3;
        int m0 = 2 * mp, m1 = 2 * mp + 1;
        float w0  = lnw[l * Mc + m0];
        float w1v = (m1 < Mc) ? lnw[l * Mc + m1] : 0.f;
        float b0  = lnb[l * Mc + m0];
        float b1v = (m1 < Mc) ? lnb[l * Mc + m1] : 0.f;
        uint2 o; o.x = bcu(pkh(w0, w1v)); o.y = bcu(pkh(b0, b1v));
        lnT[(mp * LT + lt) * 4 + il] = o;
    } else if (i < Lc * 11 + H2c) {
        int h = i - Lc * 11;
        float s = 0.f;
        for (int m = 0; m < Mc; ++m) s += w2[m * H2c + h];
        float2 t; t.x = b1[h]; t.y = s * (1.f / (float)Mc);
        bwT[h] = t;
    } else if (i == Lc * 11 + H2c) {
        float s = 0.f;
        for (int m = 0; m < Mc; ++m) s += b2[m];
        *bbarT = s * (1.f / (float)Mc);
    }
}

template<bool PACKED>
__global__ __launch_bounds__(NT) void frac2(
    const float* __restrict__ x, const float* __restrict__ orders,
    const float* __restrict__ ln_w, const float* __restrict__ ln_b,
    const float* __restrict__ w1, const float* __restrict__ b1,
    const float* __restrict__ w2, const float* __restrict__ b2,
    const uint4* __restrict__ lnq, const float2* __restrict__ bwT,
    const float* __restrict__ bbarT,
    float* __restrict__ out)
{
    __shared__ __align__(16) float xs[XPAD];
    __shared__ __align__(16) h2 xhe[NPAIR];
    __shared__ __align__(16) h2 xho[NPAIR];
    __shared__ __align__(16) float Wc[Mc][12];
    __shared__ __align__(16) h2 Wh[Mc + 1][8];
    __shared__ __align__(16) h2 w1h[H2c][12];
    __shared__ __align__(16) float2 bw[H2c];
    __shared__ float partial[NT / 64][11];
    __shared__ float Rs[11];
    __shared__ float Ey[WIN];
    __shared__ float Gt[WIN][WIN];
    __shared__ float sm1[Mc], sm2[Mc];
    __shared__ float sstat[4];

    const int bc = blockIdx.x, tid = threadIdx.x;
    const float* xg = x + (size_t)bc * Lc;

    for (int i = tid; i < Lc / 4; i += NT) {
        float4 v = reinterpret_cast<const float4*>(xg)[i];
        xs[9 + 4 * i + 0] = v.x; xs[9 + 4 * i + 1] = v.y;
        xs[9 + 4 * i + 2] = v.z; xs[9 + 4 * i + 3] = v.w;
    }
    if (tid < 9) xs[tid] = 0.f;
    for (int i = Lc + 9 + tid; i < XPAD; i += NT) xs[i] = 0.f;

    if (tid < Mc) {
        float n = orders[tid], c = 1.f;
        float wk[WIN]; wk[0] = 1.f;
        Wc[tid][0] = 1.f;
        #pragma unroll
        for (int k = 1; k < WIN; ++k) { c *= ((float)(k - 1) - n) / (float)k; Wc[tid][k] = c; wk[k] = c; }
        Wc[tid][10] = 0.f; Wc[tid][11] = 0.f;
        #pragma unroll
        for (int q = 0; q < 5; ++q) Wh[tid][q] = pkh(wk[2 * q + 1], wk[2 * q]);
        #pragma unroll
        for (int q = 5; q < 8; ++q) Wh[tid][q] = pkh(0.f, 0.f);
    }
    if (tid == Mc) {
        #pragma unroll
        for (int q = 0; q < 8; ++q) Wh[Mc][q] = pkh(0.f, 0.f);
    }
    for (int i = tid; i < H2c * 12; i += NT) {
        int h = i / 12, j = i - 12 * h;
        int m0 = 2 * j, m1 = 2 * j + 1;
        float v0 = (m0 < Mc) ? w1[h * Mc + m0] : 0.f;
        float v1 = (m1 < Mc) ? w1[h * Mc + m1] : 0.f;
        w1h[h][j] = pkh(v0, v1);
    }
    if constexpr (PACKED) {
        if (tid < H2c) bw[tid] = bwT[tid];
        if (tid == NT - 1) sstat[2] = *bbarT;
    } else {
        if (tid < H2c) {
            float s = 0.f;
            for (int m = 0; m < Mc; ++m) s += w2[m * H2c + tid];
            float2 t; t.x = b1[tid]; t.y = s * (1.f / (float)Mc);
            bw[tid] = t;
        }
        if (tid == NT - 1) {
            float s = 0.f;
            for (int m = 0; m < Mc; ++m) s += b2[m];
            sstat[2] = s * (1.f / (float)Mc);
        }
    }
    __syncthreads();   // B0: xs ready

    for (int t = tid; t < NPAIR; t += NT) {
        xhe[t] = pkh(xs[2 * t], xs[2 * t + 1]);
        xho[t] = pkh(xs[2 * t + 1], xs[2 * t + 2]);
    }

    // autocorrelation stats
    float Rp[11];
    #pragma unroll
    for (int d = 0; d < 11; ++d) Rp[d] = 0.f;
    #pragma unroll 1
    for (int g = 0; g < GROUPS; ++g) {
        const int l0 = (g * NT + tid) * NL;
        float xw[16];
        #pragma unroll
        for (int j = 0; j < 4; ++j) {
            float4 v = *reinterpret_cast<const float4*>(&xs[8 + l0 + 4 * j]);
            xw[4 * j] = v.x; xw[4 * j + 1] = v.y; xw[4 * j + 2] = v.z; xw[4 * j + 3] = v.w;
        }
        #pragma unroll
        for (int j = 0; j < 4; ++j) {
            Rp[10] += xw[1 + j];
            #pragma unroll
            for (int d = 0; d < 10; ++d) Rp[d] = fmaf(xw[1 + j], xw[1 + j + d], Rp[d]);
        }
    }
    #pragma unroll
    for (int d = 0; d < 11; ++d) {
        float v = Rp[d];
        #pragma unroll
        for (int off = 32; off >= 1; off >>= 1) v += __shfl_xor(v, off);
        if ((tid & 63) == 0) partial[tid >> 6][d] = v;
    }
    __syncthreads();   // B1
    if (tid < 11)
        Rs[tid] = partial[0][tid] + partial[1][tid] + partial[2][tid] + partial[3][tid];
    if (tid == 64) {
        float e = 0.f; Ey[0] = 0.f;
        #pragma unroll
        for (int k = 1; k < WIN; ++k) { e += xs[9 + Lc - k]; Ey[k] = e; }
    }
    __syncthreads();   // B2
    if (tid < 100) {
        int k = tid / 10, kp = tid - 10 * k;
        int dl = k > kp ? k - kp : kp - k;
        int mx = k > kp ? k : kp;
        float Bsum = 0.f;
        for (int t = Lc - mx; t <= Lc - 1 - dl; ++t) Bsum += xs[9 + t] * xs[9 + t + dl];
        Gt[k][kp] = Rs[dl] - Bsum;
    }
    __syncthreads();   // B3
    if (tid < Mc) {
        const float Sx = Rs[10];
        float s1 = 0.f, s2 = 0.f;
        #pragma unroll
        for (int k = 0; k < WIN; ++k) {
            s1 = fmaf(Wc[tid][k], Sx - Ey[k], s1);
            float inner = 0.f;
            #pragma unroll
            for (int kp = 0; kp < WIN; ++kp) inner = fmaf(Wc[tid][kp], Gt[k][kp], inner);
            s2 = fmaf(Wc[tid][k], inner, s2);
        }
        sm1[tid] = s1; sm2[tid] = s2;
    }
    __syncthreads();   // B4
    if (tid == 0) {
        float a = 0.f, b = 0.f;
        for (int m = 0; m < Mc; ++m) { a += sm1[m]; b += sm2[m]; }
        const float invN = 1.f / (float)(Lc * Mc);
        float muv = a * invN;
        float msv = b * invN;
        sstat[0] = muv;
        sstat[1] = rsqrtf(msv - muv * muv + 1e-6f);
    }
    __syncthreads();   // B5
    const float mu = sstat[0], rstd = sstat[1], bbar = sstat[2];
    h2 rs2; rs2[0] = (_Float16)rstd;  rs2[1] = (_Float16)rstd;
    h2 nm2; nm2[0] = (_Float16)(-mu); nm2[1] = (_Float16)(-mu);

    #pragma unroll 1
    for (int g = 0; g < GROUPS; ++g) {
        const int lt = g * NT + tid;          // thread's l-quad index
        const int l0 = lt * NL;
        const int t0 = l0 >> 1;
        h2 ue0, ue1, ue2, ue3, ue4, ue5, uo0, uo1, uo2, uo3, uo4, uo5;
        {
            float2 p0 = *reinterpret_cast<const float2*>(&xhe[t0]);
            float2 p1 = *reinterpret_cast<const float2*>(&xhe[t0 + 2]);
            float2 p2 = *reinterpret_cast<const float2*>(&xhe[t0 + 4]);
            ue0 = bch2(p0.x); ue1 = bch2(p0.y); ue2 = bch2(p1.x);
            ue3 = bch2(p1.y); ue4 = bch2(p2.x); ue5 = bch2(p2.y);
            float2 q0 = *reinterpret_cast<const float2*>(&xho[t0]);
            float2 q1 = *reinterpret_cast<const float2*>(&xho[t0 + 2]);
            float2 q2 = *reinterpret_cast<const float2*>(&xho[t0 + 4]);
            uo0 = bch2(q0.x); uo1 = bch2(q0.y); uo2 = bch2(q1.x);
            uo3 = bch2(q1.y); uo4 = bch2(q2.x); uo5 = bch2(q2.y);
        }
        h2 hnp[NL][11];
        const float* lwr = ln_w + (size_t)l0 * Mc;
        const float* lbr = ln_b + (size_t)l0 * Mc;
        #pragma unroll
        for (int mp = 0; mp < 11; ++mp) {
            const int m0 = 2 * mp;
            const int m1 = (mp < 10) ? (2 * mp + 1) : Mc;
            float4 wa = *reinterpret_cast<const float4*>(&Wh[m0][0]);
            h2 wa0 = bch2(wa.x), wa1 = bch2(wa.y), wa2 = bch2(wa.z), wa3 = bch2(wa.w);
            h2 wa4 = Wh[m0][4];
            float4 wb = *reinterpret_cast<const float4*>(&Wh[m1][0]);
            h2 wb0 = bch2(wb.x), wb1 = bch2(wb.y), wb2 = bch2(wb.z), wb3 = bch2(wb.w);
            h2 wb4 = Wh[m1][4];
            float d00 = fdot2f(ue0, wa4, fdot2f(ue1, wa3, fdot2f(ue2, wa2, fdot2f(ue3, wa1, fdot2f(ue4, wa0, 0.f)))));
            float d01 = fdot2f(uo0, wa4, fdot2f(uo1, wa3, fdot2f(uo2, wa2, fdot2f(uo3, wa1, fdot2f(uo4, wa0, 0.f)))));
            float d02 = fdot2f(ue1, wa4, fdot2f(ue2, wa3, fdot2f(ue3, wa2, fdot2f(ue4, wa1, fdot2f(ue5, wa0, 0.f)))));
            float d03 = fdot2f(uo1, wa4, fdot2f(uo2, wa3, fdot2f(uo3, wa2, fdot2f(uo4, wa1, fdot2f(uo5, wa0, 0.f)))));
            float d10 = fdot2f(ue0, wb4, fdot2f(ue1, wb3, fdot2f(ue2, wb2, fdot2f(ue3, wb1, fdot2f(ue4, wb0, 0.f)))));
            float d11 = fdot2f(uo0, wb4, fdot2f(uo1, wb3, fdot2f(uo2, wb2, fdot2f(uo3, wb1, fdot2f(uo4, wb0, 0.f)))));
            float d12 = fdot2f(ue1, wb4, fdot2f(ue2, wb3, fdot2f(ue3, wb2, fdot2f(ue4, wb1, fdot2f(ue5, wb0, 0.f)))));
            float d13 = fdot2f(uo1, wb4, fdot2f(uo2, wb3, fdot2f(uo3, wb2, fdot2f(uo4, wb1, fdot2f(uo5, wb0, 0.f)))));
            if constexpr (PACKED) {
                // two fully-coalesced uint4 loads: il 0,1 then il 2,3
                uint4 A = lnq[(mp * LT + lt) * 2 + 0];
                uint4 Bq = lnq[(mp * LT + lt) * 2 + 1];
                { h2 aw = bch2u(A.x) * rs2;  h2 bh = aw * nm2 + bch2u(A.y);  hnp[0][mp] = pkh(d00, d10) * aw + bh; }
                { h2 aw = bch2u(A.z) * rs2;  h2 bh = aw * nm2 + bch2u(A.w);  hnp[1][mp] = pkh(d01, d11) * aw + bh; }
                { h2 aw = bch2u(Bq.x) * rs2; h2 bh = aw * nm2 + bch2u(Bq.y); hnp[2][mp] = pkh(d02, d12) * aw + bh; }
                { h2 aw = bch2u(Bq.z) * rs2; h2 bh = aw * nm2 + bch2u(Bq.w); hnp[3][mp] = pkh(d03, d13) * aw + bh; }
            } else {
                #define AFFINE(IL, DA, DB)                                                   \
                {                                                                            \
                    float lw0 = lwr[(IL) * Mc + m0];                                         \
                    float lb0 = lbr[(IL) * Mc + m0];                                         \
                    float lw1 = (mp < 10) ? lwr[(IL) * Mc + m0 + 1] : 0.f;                   \
                    float lb1 = (mp < 10) ? lbr[(IL) * Mc + m0 + 1] : 0.f;                   \
                    float a0 = rstd * lw0, a1 = rstd * lw1;                                  \
                    float h0 = fmaf(DA - mu, a0, lb0);                                       \
                    float h1 = fmaf(DB - mu, a1, lb1);                                       \
                    hnp[IL][mp] = pkh(h0, h1);                                               \
                }
                AFFINE(0, d00, d10) AFFINE(1, d01, d11) AFFINE(2, d02, d12) AFFINE(3, d03, d13)
                #undef AFFINE
            }
        }
        float acc0 = 0.f, acc1 = 0.f, acc2 = 0.f, acc3 = 0.f;
        #pragma unroll 1
        for (int h = 0; h < H2c; ++h) {
            float4 a = *reinterpret_cast<const float4*>(&w1h[h][0]);
            float4 b4 = *reinterpret_cast<const float4*>(&w1h[h][4]);
            float4 c4 = *reinterpret_cast<const float4*>(&w1h[h][8]);
            h2 wj0 = bch2(a.x), wj1 = bch2(a.y), wj2 = bch2(a.z), wj3 = bch2(a.w);
            h2 wj4 = bch2(b4.x), wj5 = bch2(b4.y), wj6 = bch2(b4.z), wj7 = bch2(b4.w);
            h2 wj8 = bch2(c4.x), wj9 = bch2(c4.y), wj10 = bch2(c4.z);
            float2 bwv = bw[h];
            #define DOT11(TI, IL)                                                            \
                float TI = bwv.x;                                                            \
                TI = fdot2f(hnp[IL][0], wj0, TI);  TI = fdot2f(hnp[IL][1], wj1, TI);         \
                TI = fdot2f(hnp[IL][2], wj2, TI);  TI = fdot2f(hnp[IL][3], wj3, TI);         \
                TI = fdot2f(hnp[IL][4], wj4, TI);  TI = fdot2f(hnp[IL][5], wj5, TI);         \
                TI = fdot2f(hnp[IL][6], wj6, TI);  TI = fdot2f(hnp[IL][7], wj7, TI);         \
                TI = fdot2f(hnp[IL][8], wj8, TI);  TI = fdot2f(hnp[IL][9], wj9, TI);         \
                TI = fdot2f(hnp[IL][10], wj10, TI);
            DOT11(tv0, 0) DOT11(tv1, 1) DOT11(tv2, 2) DOT11(tv3, 3)
            #undef DOT11
            acc0 = fmaf(gelu_f(tv0), bwv.y, acc0);
            acc1 = fmaf(gelu_f(tv1), bwv.y, acc1);
            acc2 = fmaf(gelu_f(tv2), bwv.y, acc2);
            acc3 = fmaf(gelu_f(tv3), bwv.y, acc3);
        }
        float4 o;
        o.x = xs[9 + l0 + 0] + acc0 + bbar;
        o.y = xs[9 + l0 + 1] + acc1 + bbar;
        o.z = xs[9 + l0 + 2] + acc2 + bbar;
        o.w = xs[9 + l0 + 3] + acc3 + bbar;
        *reinterpret_cast<float4*>(&out[(size_t)bc * Lc + l0]) = o;
    }
}

extern "C" void kernel_launch(void* const* d_in, const int* in_sizes, int n_in,
                              void* d_out, int out_size, void* d_ws, size_t ws_size,
                              hipStream_t stream) {
    const float* x      = (const float*)d_in[0];
    const float* orders = (const float*)d_in[1];
    const float* ln_w   = (const float*)d_in[2];
    const float* ln_b   = (const float*)d_in[3];
    const float* w1     = (const float*)d_in[4];
    const float* b1     = (const float*)d_in[5];
    const float* w2     = (const float*)d_in[6];
    const float* b2     = (const float*)d_in[7];
    float* out = (float*)d_out;

    const int nbc = in_sizes[0] / Lc;   // B*C = 1472
    if (ws_size >= WS_NEED) {
        uint2*  lnT   = (uint2*)d_ws;
        float2* bwT   = (float2*)((char*)d_ws + WS_BW_OFF);
        float*  bbarT = (float*)((char*)d_ws + WS_BBAR_OFF);
        const int npre = Lc * 11 + H2c + 1;
        repack_all<<<(npre + 255) / 256, 256, 0, stream>>>(ln_w, ln_b, w1, b1, w2, b2,
                                                           lnT, bwT, bbarT);
        frac2<true><<<nbc, NT, 0, stream>>>(x, orders, ln_w, ln_b, w1, b1, w2, b2,
                                            (const uint4*)lnT, (const float2*)bwT,
                                            (const float*)bbarT, out);
    } else {
        frac2<false><<<nbc, NT, 0, stream>>>(x, orders, ln_w, ln_b, w1, b1, w2, b2,
                                             nullptr, nullptr, nullptr, out);
    }
}

// Round 6
// 92.851 us; speedup vs baseline: 4.5966x; 1.2869x over previous
//
#include <hip/hip_runtime.h>
#include <cstdint>
#include <cstddef>

typedef _Float16 h2   __attribute__((ext_vector_type(2)));
typedef __fp16  h2fp  __attribute__((ext_vector_type(2)));
typedef _Float16 f16x8 __attribute__((ext_vector_type(8)));
typedef float   f32x4 __attribute__((ext_vector_type(4)));

#define NT 256
constexpr int Lc   = 2048;
constexpr int Mc   = 21;
constexpr int WIN  = 10;
constexpr int H2c  = 42;
constexpr int NL   = 4;                  // stats pass only
constexpr int GROUPS = Lc / (NT * NL);   // 2 (stats pass only)
constexpr int XPAD  = 2080;
constexpr int NPAIR = Lc / 2 + 8;        // 1032
constexpr int NTILE = Lc / 16;           // 128 l-tiles
constexpr int TPW   = NTILE / 4;         // 32 tiles per wave
// ws: lnT[tile][lane][2] uint4 (lw-quad, lb-quad) = 128*64*32 B
constexpr size_t WS_NEED = (size_t)NTILE * 64 * 32;

__device__ __forceinline__ h2 pkh(float a, float b) {
    h2fp r = __builtin_amdgcn_cvt_pkrtz(a, b);
    return __builtin_bit_cast(h2, r);
}
__device__ __forceinline__ float fdot2f(h2 a, h2 b, float c) {
    return __builtin_amdgcn_fdot2(a, b, c, false);
}
__device__ __forceinline__ float gelu_f(float t) {
    const float C0z = 0.79788456080286536f * 2.8853900817779268f;
    const float C1z = 0.035677408136300125f * 2.8853900817779268f;
    float t2 = t * t;
    float z  = t * fmaf(C1z, t2, C0z);
    float v  = __builtin_amdgcn_exp2f(z);
    float r  = __builtin_amdgcn_rcpf(1.f + v);
    return fmaf(-t, r, t);
}
__device__ __forceinline__ h2 bch2(float x)     { return __builtin_bit_cast(h2, x); }
__device__ __forceinline__ h2 bch2u(unsigned x) { return __builtin_bit_cast(h2, x); }
__device__ __forceinline__ unsigned bcu(h2 x)   { return __builtin_bit_cast(unsigned, x); }

// Pre-kernel: per (l-tile, lane) pack lw/lb f16 quads matching the per-lane
// (l = lane&15, m = (lane>>4)*8 + j) assignment. m==21 is the bias row
// (lw=0, lb=1); m>21 zero.
__global__ __launch_bounds__(256) void repack_ln3(
    const float* __restrict__ lnw, const float* __restrict__ lnb,
    uint4* __restrict__ dst)
{
    int i = blockIdx.x * 256 + threadIdx.x;
    if (i >= NTILE * 64) return;
    int lt = i >> 6, lane = i & 63;
    int l  = lt * 16 + (lane & 15);
    int m0 = (lane >> 4) * 8;
    unsigned lwq[4], lbq[4];
    #pragma unroll
    for (int p = 0; p < 4; ++p) {
        int ma = m0 + 2 * p, mb = ma + 1;
        float lwa = (ma < Mc) ? lnw[l * Mc + ma] : 0.f;
        float lwb = (mb < Mc) ? lnw[l * Mc + mb] : 0.f;
        float lba = (ma < Mc) ? lnb[l * Mc + ma] : ((ma == Mc) ? 1.f : 0.f);
        float lbb = (mb < Mc) ? lnb[l * Mc + mb] : ((mb == Mc) ? 1.f : 0.f);
        lwq[p] = bcu(pkh(lwa, lwb));
        lbq[p] = bcu(pkh(lba, lbb));
    }
    uint4 a; a.x = lwq[0]; a.y = lwq[1]; a.z = lwq[2]; a.w = lwq[3];
    uint4 b; b.x = lbq[0]; b.y = lbq[1]; b.z = lbq[2]; b.w = lbq[3];
    dst[(size_t)i * 2 + 0] = a;
    dst[(size_t)i * 2 + 1] = b;
}

template<bool PACKED>
__global__ __launch_bounds__(NT) void frac3(
    const float* __restrict__ x, const float* __restrict__ orders,
    const float* __restrict__ ln_w, const float* __restrict__ ln_b,
    const float* __restrict__ w1, const float* __restrict__ b1,
    const float* __restrict__ w2, const float* __restrict__ b2,
    const uint4* __restrict__ lnq,
    float* __restrict__ out)
{
    __shared__ __align__(16) float xs[XPAD];
    __shared__ __align__(16) h2 xhe[NPAIR];
    __shared__ __align__(16) h2 xho[NPAIR];
    __shared__ __align__(16) float Wc[Mc][12];
    __shared__ __align__(16) h2 Wh[32][8];      // conv pairs, rows m>=21 zero
    __shared__ __align__(16) h2 w1h[48][16];    // [h][m-pair]; col 21 = b1; pad 0
    __shared__ float wbars[48];
    __shared__ float partial[NT / 64][11];
    __shared__ float Rs[11];
    __shared__ float Ey[WIN];
    __shared__ float Gt[WIN][WIN];
    __shared__ float sm1[Mc], sm2[Mc];
    __shared__ float sstat[4];

    const int bc = blockIdx.x, tid = threadIdx.x;
    const int lane = tid & 63, wid = tid >> 6;
    const float* xg = x + (size_t)bc * Lc;

    // ---- stage x (padded) ----
    for (int i = tid; i < Lc / 4; i += NT) {
        float4 v = reinterpret_cast<const float4*>(xg)[i];
        xs[9 + 4 * i + 0] = v.x; xs[9 + 4 * i + 1] = v.y;
        xs[9 + 4 * i + 2] = v.z; xs[9 + 4 * i + 3] = v.w;
    }
    if (tid < 9) xs[tid] = 0.f;
    for (int i = Lc + 9 + tid; i < XPAD; i += NT) xs[i] = 0.f;

    // ---- coefficients ----
    if (tid < Mc) {
        float n = orders[tid], c = 1.f;
        float wk[WIN]; wk[0] = 1.f;
        Wc[tid][0] = 1.f;
        #pragma unroll
        for (int k = 1; k < WIN; ++k) { c *= ((float)(k - 1) - n) / (float)k; Wc[tid][k] = c; wk[k] = c; }
        Wc[tid][10] = 0.f; Wc[tid][11] = 0.f;
        #pragma unroll
        for (int q = 0; q < 5; ++q) Wh[tid][q] = pkh(wk[2 * q + 1], wk[2 * q]);
        #pragma unroll
        for (int q = 5; q < 8; ++q) Wh[tid][q] = pkh(0.f, 0.f);
    } else if (tid < 32) {
        #pragma unroll
        for (int q = 0; q < 8; ++q) Wh[tid][q] = pkh(0.f, 0.f);
    }
    // w1 (f16, padded, bias row at m=21)
    for (int i = tid; i < 48 * 16; i += NT) {
        int h = i >> 4, p = i & 15;
        int ma = 2 * p, mb = 2 * p + 1;
        float v0 = 0.f, v1 = 0.f;
        if (h < H2c) {
            v0 = (ma < Mc) ? w1[h * Mc + ma] : ((ma == Mc) ? b1[h] : 0.f);
            v1 = (mb < Mc) ? w1[h * Mc + mb] : ((mb == Mc) ? b1[h] : 0.f);
        }
        w1h[h][p] = pkh(v0, v1);
    }
    if (tid < 48) {
        float s = 0.f;
        if (tid < H2c) {
            for (int m = 0; m < Mc; ++m) s += w2[m * H2c + tid];
            s *= (1.f / (float)Mc);
        }
        wbars[tid] = s;
    }
    if (tid == NT - 1) {
        float s = 0.f;
        for (int m = 0; m < Mc; ++m) s += b2[m];
        sstat[2] = s * (1.f / (float)Mc);
    }
    __syncthreads();   // B0

    // ---- f16 pair images ----
    for (int t = tid; t < NPAIR; t += NT) {
        xhe[t] = pkh(xs[2 * t], xs[2 * t + 1]);
        xho[t] = pkh(xs[2 * t + 1], xs[2 * t + 2]);
    }

    // ---- autocorrelation stats (unchanged, verified) ----
    float Rp[11];
    #pragma unroll
    for (int d = 0; d < 11; ++d) Rp[d] = 0.f;
    #pragma unroll 1
    for (int g = 0; g < GROUPS; ++g) {
        const int l0 = (g * NT + tid) * NL;
        float xw[16];
        #pragma unroll
        for (int j = 0; j < 4; ++j) {
            float4 v = *reinterpret_cast<const float4*>(&xs[8 + l0 + 4 * j]);
            xw[4 * j] = v.x; xw[4 * j + 1] = v.y; xw[4 * j + 2] = v.z; xw[4 * j + 3] = v.w;
        }
        #pragma unroll
        for (int j = 0; j < 4; ++j) {
            Rp[10] += xw[1 + j];
            #pragma unroll
            for (int d = 0; d < 10; ++d) Rp[d] = fmaf(xw[1 + j], xw[1 + j + d], Rp[d]);
        }
    }
    #pragma unroll
    for (int d = 0; d < 11; ++d) {
        float v = Rp[d];
        #pragma unroll
        for (int off = 32; off >= 1; off >>= 1) v += __shfl_xor(v, off);
        if ((tid & 63) == 0) partial[tid >> 6][d] = v;
    }
    __syncthreads();   // B1
    if (tid < 11)
        Rs[tid] = partial[0][tid] + partial[1][tid] + partial[2][tid] + partial[3][tid];
    if (tid == 64) {
        float e = 0.f; Ey[0] = 0.f;
        #pragma unroll
        for (int k = 1; k < WIN; ++k) { e += xs[9 + Lc - k]; Ey[k] = e; }
    }
    __syncthreads();   // B2
    if (tid < 100) {
        int k = tid / 10, kp = tid - 10 * k;
        int dl = k > kp ? k - kp : kp - k;
        int mx = k > kp ? k : kp;
        float Bsum = 0.f;
        for (int t = Lc - mx; t <= Lc - 1 - dl; ++t) Bsum += xs[9 + t] * xs[9 + t + dl];
        Gt[k][kp] = Rs[dl] - Bsum;
    }
    __syncthreads();   // B3
    if (tid < Mc) {
        const float Sx = Rs[10];
        float s1 = 0.f, s2 = 0.f;
        #pragma unroll
        for (int k = 0; k < WIN; ++k) {
            s1 = fmaf(Wc[tid][k], Sx - Ey[k], s1);
            float inner = 0.f;
            #pragma unroll
            for (int kp = 0; kp < WIN; ++kp) inner = fmaf(Wc[tid][kp], Gt[k][kp], inner);
            s2 = fmaf(Wc[tid][k], inner, s2);
        }
        sm1[tid] = s1; sm2[tid] = s2;
    }
    __syncthreads();   // B4
    if (tid == 0) {
        float a = 0.f, b = 0.f;
        for (int m = 0; m < Mc; ++m) { a += sm1[m]; b += sm2[m]; }
        const float invN = 1.f / (float)(Lc * Mc);
        float muv = a * invN;
        float msv = b * invN;
        sstat[0] = muv;
        sstat[1] = rsqrtf(msv - muv * muv + 1e-6f);
    }
    __syncthreads();   // B5
    const float mu = sstat[0], rstd = sstat[1], bbar = sstat[2];
    h2 rs2; rs2[0] = (_Float16)rstd;  rs2[1] = (_Float16)rstd;
    h2 nm2; nm2[0] = (_Float16)(-mu); nm2[1] = (_Float16)(-mu);

    // ---- per-lane role: l = li (within tile), m = gq*8 + j ----
    const int li = lane & 15, gq = lane >> 4;
    const int m0 = gq * 8;

    // conv coef regs (8 rows x 5 pairs)
    h2 Wreg[8][5];
    #pragma unroll
    for (int j = 0; j < 8; ++j) {
        uint4 r4 = *reinterpret_cast<const uint4*>(&Wh[m0 + j][0]);
        Wreg[j][0] = bch2u(r4.x); Wreg[j][1] = bch2u(r4.y);
        Wreg[j][2] = bch2u(r4.z); Wreg[j][3] = bch2u(r4.w);
        Wreg[j][4] = Wh[m0 + j][4];
    }
    // w1 A-fragments: row h = t*16+li, k = m0..m0+7
    f16x8 Afrag[3];
    #pragma unroll
    for (int t = 0; t < 3; ++t) {
        uint4 r4 = *reinterpret_cast<const uint4*>(&w1h[t * 16 + li][gq * 4]);
        Afrag[t] = __builtin_bit_cast(f16x8, r4);
    }
    float wbreg[12];
    #pragma unroll
    for (int t = 0; t < 3; ++t)
        #pragma unroll
        for (int r = 0; r < 4; ++r)
            wbreg[t * 4 + r] = wbars[t * 16 + gq * 4 + r];

    const h2* xbase = (li & 1) ? xho : xhe;
    const int c0 = li >> 1;

    // ---- main loop: 1 l-tile (16 l x 48 h) per iteration ----
    #pragma unroll 1
    for (int it = 0; it < TPW; ++it) {
        const int lt = wid * TPW + it;
        const int l  = lt * 16 + li;
        const int t0 = lt * 8 + c0;

        h2 u0 = xbase[t0 + 0], u1 = xbase[t0 + 1], u2 = xbase[t0 + 2];
        h2 u3 = xbase[t0 + 3], u4 = xbase[t0 + 4];

        float d[8];
        #pragma unroll
        for (int j = 0; j < 8; ++j)
            d[j] = fdot2f(u0, Wreg[j][4], fdot2f(u1, Wreg[j][3],
                   fdot2f(u2, Wreg[j][2], fdot2f(u3, Wreg[j][1],
                   fdot2f(u4, Wreg[j][0], 0.f)))));

        h2 lw2[4], lb2[4];
        if constexpr (PACKED) {
            uint4 A  = lnq[((size_t)lt * 64 + lane) * 2 + 0];
            uint4 Bv = lnq[((size_t)lt * 64 + lane) * 2 + 1];
            lw2[0] = bch2u(A.x);  lw2[1] = bch2u(A.y);
            lw2[2] = bch2u(A.z);  lw2[3] = bch2u(A.w);
            lb2[0] = bch2u(Bv.x); lb2[1] = bch2u(Bv.y);
            lb2[2] = bch2u(Bv.z); lb2[3] = bch2u(Bv.w);
        } else {
            #pragma unroll
            for (int p = 0; p < 4; ++p) {
                int ma = m0 + 2 * p, mb = ma + 1;
                float lwa = (ma < Mc) ? ln_w[(size_t)l * Mc + ma] : 0.f;
                float lwb = (mb < Mc) ? ln_w[(size_t)l * Mc + mb] : 0.f;
                float lba = (ma < Mc) ? ln_b[(size_t)l * Mc + ma] : ((ma == Mc) ? 1.f : 0.f);
                float lbb = (mb < Mc) ? ln_b[(size_t)l * Mc + mb] : ((mb == Mc) ? 1.f : 0.f);
                lw2[p] = pkh(lwa, lwb);
                lb2[p] = pkh(lba, lbb);
            }
        }

        // affine -> B-fragment (f16)
        unsigned Bu0, Bu1, Bu2, Bu3;
        {
            h2 dp, aw, hn;
            dp = pkh(d[0], d[1]); aw = lw2[0] * rs2; hn = dp * aw + (nm2 * aw + lb2[0]); Bu0 = bcu(hn);
            dp = pkh(d[2], d[3]); aw = lw2[1] * rs2; hn = dp * aw + (nm2 * aw + lb2[1]); Bu1 = bcu(hn);
            dp = pkh(d[4], d[5]); aw = lw2[2] * rs2; hn = dp * aw + (nm2 * aw + lb2[2]); Bu2 = bcu(hn);
            dp = pkh(d[6], d[7]); aw = lw2[3] * rs2; hn = dp * aw + (nm2 * aw + lb2[3]); Bu3 = bcu(hn);
        }
        uint4 Bq; Bq.x = Bu0; Bq.y = Bu1; Bq.z = Bu2; Bq.w = Bu3;
        f16x8 Bfrag = __builtin_bit_cast(f16x8, Bq);

        f32x4 z = {0.f, 0.f, 0.f, 0.f};
        f32x4 cf0 = __builtin_amdgcn_mfma_f32_16x16x32_f16(Afrag[0], Bfrag, z, 0, 0, 0);
        f32x4 cf1 = __builtin_amdgcn_mfma_f32_16x16x32_f16(Afrag[1], Bfrag, z, 0, 0, 0);
        f32x4 cf2 = __builtin_amdgcn_mfma_f32_16x16x32_f16(Afrag[2], Bfrag, z, 0, 0, 0);

        float acc = 0.f;
        acc = fmaf(gelu_f(cf0[0]), wbreg[0],  acc);
        acc = fmaf(gelu_f(cf0[1]), wbreg[1],  acc);
        acc = fmaf(gelu_f(cf0[2]), wbreg[2],  acc);
        acc = fmaf(gelu_f(cf0[3]), wbreg[3],  acc);
        acc = fmaf(gelu_f(cf1[0]), wbreg[4],  acc);
        acc = fmaf(gelu_f(cf1[1]), wbreg[5],  acc);
        acc = fmaf(gelu_f(cf1[2]), wbreg[6],  acc);
        acc = fmaf(gelu_f(cf1[3]), wbreg[7],  acc);
        acc = fmaf(gelu_f(cf2[0]), wbreg[8],  acc);
        acc = fmaf(gelu_f(cf2[1]), wbreg[9],  acc);
        acc = fmaf(gelu_f(cf2[2]), wbreg[10], acc);
        acc = fmaf(gelu_f(cf2[3]), wbreg[11], acc);

        acc += __shfl_xor(acc, 16);
        acc += __shfl_xor(acc, 32);

        if (lane < 16)
            out[(size_t)bc * Lc + l] = xs[9 + l] + acc + bbar;
    }
}

extern "C" void kernel_launch(void* const* d_in, const int* in_sizes, int n_in,
                              void* d_out, int out_size, void* d_ws, size_t ws_size,
                              hipStream_t stream) {
    const float* x      = (const float*)d_in[0];
    const float* orders = (const float*)d_in[1];
    const float* ln_w   = (const float*)d_in[2];
    const float* ln_b   = (const float*)d_in[3];
    const float* w1     = (const float*)d_in[4];
    const float* b1     = (const float*)d_in[5];
    const float* w2     = (const float*)d_in[6];
    const float* b2     = (const float*)d_in[7];
    float* out = (float*)d_out;

    const int nbc = in_sizes[0] / Lc;   // B*C = 1472
    if (ws_size >= WS_NEED) {
        uint4* lnT = (uint4*)d_ws;
        repack_ln3<<<(NTILE * 64 + 255) / 256, 256, 0, stream>>>(ln_w, ln_b, lnT);
        frac3<true><<<nbc, NT, 0, stream>>>(x, orders, ln_w, ln_b, w1, b1, w2, b2,
                                            (const uint4*)lnT, out);
    } else {
        frac3<false><<<nbc, NT, 0, stream>>>(x, orders, ln_w, ln_b, w1, b1, w2, b2,
                                             nullptr, out);
    }
}

// Round 7
// 78.672 us; speedup vs baseline: 5.4250x; 1.1802x over previous
//
#include <hip/hip_runtime.h>
#include <cstdint>
#include <cstddef>

typedef _Float16 h2    __attribute__((ext_vector_type(2)));
typedef __fp16   h2fp  __attribute__((ext_vector_type(2)));
typedef _Float16 f16x8 __attribute__((ext_vector_type(8)));
typedef float    f32x4 __attribute__((ext_vector_type(4)));

#define NT 256
constexpr int Lc   = 2048;
constexpr int Mc   = 21;
constexpr int WIN  = 10;
constexpr int H2c  = 42;
constexpr int NL   = 4;                  // stats pass only
constexpr int GROUPS = Lc / (NT * NL);   // 2
constexpr int XPAD  = 2080;
constexpr int NPAIR = Lc / 2 + 8;        // 1032
constexpr int NTILE = Lc / 16;           // 128
constexpr int TPW   = NTILE / 4;         // 32
constexpr size_t WS_NEED = (size_t)NTILE * 64 * 32;

__device__ __forceinline__ h2 pkh(float a, float b) {
    h2fp r = __builtin_amdgcn_cvt_pkrtz(a, b);
    return __builtin_bit_cast(h2, r);
}
__device__ __forceinline__ float gelu_f(float t) {
    const float C0z = 0.79788456080286536f * 2.8853900817779268f;
    const float C1z = 0.035677408136300125f * 2.8853900817779268f;
    float t2 = t * t;
    float z  = t * fmaf(C1z, t2, C0z);
    float v  = __builtin_amdgcn_exp2f(z);
    float r  = __builtin_amdgcn_rcpf(1.f + v);
    return fmaf(-t, r, t);
}
__device__ __forceinline__ h2 bch2u(unsigned x) { return __builtin_bit_cast(h2, x); }
__device__ __forceinline__ unsigned bcu(h2 x)   { return __builtin_bit_cast(unsigned, x); }
__device__ __forceinline__ unsigned swap16(unsigned u) { return (u >> 16) | (u << 16); }

// sigma: k-slot s=(gq*8+j) -> physical m; pairs p=0..3 within lane
__device__ __forceinline__ int sigma_pair(int gq, int p) {
    return (p < 2) ? (4 * gq + 2 * p) : (16 + 4 * gq + 2 * (p - 2));
}

// Pre-kernel: per (l-tile, lane) pack sigma-permuted lw/lb f16 quads.
__global__ __launch_bounds__(256) void repack_ln4(
    const float* __restrict__ lnw, const float* __restrict__ lnb,
    uint4* __restrict__ dst)
{
    int i = blockIdx.x * 256 + threadIdx.x;
    if (i >= NTILE * 64) return;
    int lt = i >> 6, lane = i & 63;
    int l  = lt * 16 + (lane & 15);
    int gq = lane >> 4;
    unsigned lwq[4], lbq[4];
    #pragma unroll
    for (int p = 0; p < 4; ++p) {
        int ma = sigma_pair(gq, p), mb = ma + 1;
        float lwa = (ma < Mc) ? lnw[l * Mc + ma] : 0.f;
        float lwb = (mb < Mc) ? lnw[l * Mc + mb] : 0.f;
        float lba = (ma < Mc) ? lnb[l * Mc + ma] : ((ma == Mc) ? 1.f : 0.f);
        float lbb = (mb < Mc) ? lnb[l * Mc + mb] : ((mb == Mc) ? 1.f : 0.f);
        lwq[p] = bcu(pkh(lwa, lwb));
        lbq[p] = bcu(pkh(lba, lbb));
    }
    uint4 a; a.x = lwq[0]; a.y = lwq[1]; a.z = lwq[2]; a.w = lwq[3];
    uint4 b; b.x = lbq[0]; b.y = lbq[1]; b.z = lbq[2]; b.w = lbq[3];
    dst[(size_t)i * 2 + 0] = a;
    dst[(size_t)i * 2 + 1] = b;
}

template<bool PACKED>
__global__ __launch_bounds__(NT, 4) void frac4(
    const float* __restrict__ x, const float* __restrict__ orders,
    const float* __restrict__ ln_w, const float* __restrict__ ln_b,
    const float* __restrict__ w1, const float* __restrict__ b1,
    const float* __restrict__ w2, const float* __restrict__ b2,
    const uint4* __restrict__ lnq,
    float* __restrict__ out)
{
    __shared__ __align__(16) float xs[XPAD];
    __shared__ __align__(16) h2 xhe[NPAIR];
    __shared__ __align__(16) h2 xho[NPAIR];
    __shared__ __align__(16) float Wc[Mc][12];
    __shared__ __align__(16) h2 w1h[48][16];    // sigma-permuted k-pairs; s=13 is b1
    __shared__ float wbars[48];
    __shared__ float partial[NT / 64][11];
    __shared__ float Rs[11];
    __shared__ float Ey[WIN];
    __shared__ float Gt[WIN][WIN];
    __shared__ float sm1[Mc], sm2[Mc];
    __shared__ float sstat[4];

    const int bc = blockIdx.x, tid = threadIdx.x;
    const int lane = tid & 63, wid = tid >> 6;
    const float* xg = x + (size_t)bc * Lc;

    // ---- stage x (padded) ----
    for (int i = tid; i < Lc / 4; i += NT) {
        float4 v = reinterpret_cast<const float4*>(xg)[i];
        xs[9 + 4 * i + 0] = v.x; xs[9 + 4 * i + 1] = v.y;
        xs[9 + 4 * i + 2] = v.z; xs[9 + 4 * i + 3] = v.w;
    }
    if (tid < 9) xs[tid] = 0.f;
    for (int i = Lc + 9 + tid; i < XPAD; i += NT) xs[i] = 0.f;

    // ---- fracdiff coefficients (f32, used by stats + conv A-frag) ----
    if (tid < Mc) {
        float n = orders[tid], c = 1.f;
        Wc[tid][0] = 1.f;
        #pragma unroll
        for (int k = 1; k < WIN; ++k) { c *= ((float)(k - 1) - n) / (float)k; Wc[tid][k] = c; }
        Wc[tid][10] = 0.f; Wc[tid][11] = 0.f;
    }
    // ---- w1 pack, sigma-permuted; global pair p: s=2p,2p+1 ----
    for (int i = tid; i < 48 * 16; i += NT) {
        int h = i >> 4, p = i & 15;
        int s0 = 2 * p;
        int gq0 = s0 >> 3, j0 = s0 & 7;
        int m_a = (j0 < 4) ? (4 * gq0 + j0) : (16 + 4 * gq0 + (j0 - 4));
        int m_b = m_a + 1;
        float v0 = 0.f, v1 = 0.f;
        if (h < H2c) {
            v0 = (m_a < Mc) ? w1[h * Mc + m_a] : ((m_a == Mc) ? b1[h] : 0.f);
            v1 = (m_b < Mc) ? w1[h * Mc + m_b] : ((m_b == Mc) ? b1[h] : 0.f);
        }
        w1h[h][p] = pkh(v0, v1);
    }
    if (tid < 48) {
        float s = 0.f;
        if (tid < H2c) {
            for (int m = 0; m < Mc; ++m) s += w2[m * H2c + tid];
            s *= (1.f / (float)Mc);
        }
        wbars[tid] = s;
    }
    if (tid == NT - 1) {
        float s = 0.f;
        for (int m = 0; m < Mc; ++m) s += b2[m];
        sstat[2] = s * (1.f / (float)Mc);
    }
    __syncthreads();   // B0

    // ---- f16 pair images ----
    for (int t = tid; t < NPAIR; t += NT) {
        xhe[t] = pkh(xs[2 * t], xs[2 * t + 1]);
        xho[t] = pkh(xs[2 * t + 1], xs[2 * t + 2]);
    }

    // ---- autocorrelation stats ----
    float Rp[11];
    #pragma unroll
    for (int d = 0; d < 11; ++d) Rp[d] = 0.f;
    #pragma unroll 1
    for (int g = 0; g < GROUPS; ++g) {
        const int l0 = (g * NT + tid) * NL;
        float xw[16];
        #pragma unroll
        for (int j = 0; j < 4; ++j) {
            float4 v = *reinterpret_cast<const float4*>(&xs[8 + l0 + 4 * j]);
            xw[4 * j] = v.x; xw[4 * j + 1] = v.y; xw[4 * j + 2] = v.z; xw[4 * j + 3] = v.w;
        }
        #pragma unroll
        for (int j = 0; j < 4; ++j) {
            Rp[10] += xw[1 + j];
            #pragma unroll
            for (int d = 0; d < 10; ++d) Rp[d] = fmaf(xw[1 + j], xw[1 + j + d], Rp[d]);
        }
    }
    #pragma unroll
    for (int d = 0; d < 11; ++d) {
        float v = Rp[d];
        #pragma unroll
        for (int off = 32; off >= 1; off >>= 1) v += __shfl_xor(v, off);
        if ((tid & 63) == 0) partial[tid >> 6][d] = v;
    }
    __syncthreads();   // B1
    if (tid < 11)
        Rs[tid] = partial[0][tid] + partial[1][tid] + partial[2][tid] + partial[3][tid];
    if (tid == 64) {
        float e = 0.f; Ey[0] = 0.f;
        #pragma unroll
        for (int k = 1; k < WIN; ++k) { e += xs[9 + Lc - k]; Ey[k] = e; }
    }
    __syncthreads();   // B2
    if (tid < 100) {
        int k = tid / 10, kp = tid - 10 * k;
        int dl = k > kp ? k - kp : kp - k;
        int mx = k > kp ? k : kp;
        float Bsum = 0.f;
        for (int t = Lc - mx; t <= Lc - 1 - dl; ++t) Bsum += xs[9 + t] * xs[9 + t + dl];
        Gt[k][kp] = Rs[dl] - Bsum;
    }
    __syncthreads();   // B3
    if (tid < Mc) {
        const float Sx = Rs[10];
        float s1 = 0.f, s2 = 0.f;
        #pragma unroll
        for (int k = 0; k < WIN; ++k) {
            s1 = fmaf(Wc[tid][k], Sx - Ey[k], s1);
            float inner = 0.f;
            #pragma unroll
            for (int kp = 0; kp < WIN; ++kp) inner = fmaf(Wc[tid][kp], Gt[k][kp], inner);
            s2 = fmaf(Wc[tid][k], inner, s2);
        }
        sm1[tid] = s1; sm2[tid] = s2;
    }
    __syncthreads();   // B4
    if (tid == 0) {
        float a = 0.f, b = 0.f;
        for (int m = 0; m < Mc; ++m) { a += sm1[m]; b += sm2[m]; }
        const float invN = 1.f / (float)(Lc * Mc);
        float muv = a * invN;
        float msv = b * invN;
        sstat[0] = muv;
        sstat[1] = rsqrtf(msv - muv * muv + 1e-6f);
    }
    __syncthreads();   // B5
    const float mu = sstat[0], rstd = sstat[1], bbar = sstat[2];
    h2 rs2; rs2[0] = (_Float16)rstd;  rs2[1] = (_Float16)rstd;
    h2 nm2; nm2[0] = (_Float16)(-mu); nm2[1] = (_Float16)(-mu);

    const int li = lane & 15, gq = lane >> 4;

    // ---- conv A-fragments: A[m, k] = W[m, k] (k<10), rows 16..20 in tile1 ----
    f16x8 WA0, WA1;
    {
        float wv0[8], wv1[8];
        const int r1 = 16 + li;
        #pragma unroll
        for (int j = 0; j < 8; ++j) {
            int k = gq * 8 + j;
            wv0[j] = (k < WIN) ? Wc[li][k] : 0.f;
            wv1[j] = (k < WIN && r1 < Mc) ? Wc[r1][k] : 0.f;
        }
        uint4 a, b;
        a.x = bcu(pkh(wv0[0], wv0[1])); a.y = bcu(pkh(wv0[2], wv0[3]));
        a.z = bcu(pkh(wv0[4], wv0[5])); a.w = bcu(pkh(wv0[6], wv0[7]));
        b.x = bcu(pkh(wv1[0], wv1[1])); b.y = bcu(pkh(wv1[2], wv1[3]));
        b.z = bcu(pkh(wv1[4], wv1[5])); b.w = bcu(pkh(wv1[6], wv1[7]));
        WA0 = __builtin_bit_cast(f16x8, a);
        WA1 = __builtin_bit_cast(f16x8, b);
    }
    // ---- MLP A-fragments + folded w2 ----
    f16x8 Afrag[3];
    #pragma unroll
    for (int t = 0; t < 3; ++t) {
        uint4 r4 = *reinterpret_cast<const uint4*>(&w1h[t * 16 + li][gq * 4]);
        Afrag[t] = __builtin_bit_cast(f16x8, r4);
    }
    float wbreg[12];
    #pragma unroll
    for (int t = 0; t < 3; ++t)
        #pragma unroll
        for (int r = 0; r < 4; ++r)
            wbreg[t * 4 + r] = wbars[t * 16 + gq * 4 + r];

    const h2* xb = (li & 1) ? xho : xhe;

    // ---- main loop ----
    #pragma unroll 1
    for (int it = 0; it < TPW; ++it) {
        const int lt = wid * TPW + it;
        const int l  = lt * 16 + li;

        // conv B-frag: word p = (xs[s-2p], xs[s-2p-1]), s = l+9-8gq
        unsigned cb0 = 0, cb1 = 0, cb2 = 0, cb3 = 0;
        {
            const int s = l + 9 - gq * 8;
            const int idx0 = (li & 1) ? (s >> 1) - 1 : (s - 1) >> 1;
            if (gq == 0) {
                cb0 = swap16(bcu(xb[idx0 - 0]));
                cb1 = swap16(bcu(xb[idx0 - 1]));
                cb2 = swap16(bcu(xb[idx0 - 2]));
                cb3 = swap16(bcu(xb[idx0 - 3]));
            } else if (gq == 1) {
                cb0 = swap16(bcu(xb[idx0]));
            }
        }
        uint4 cbq; cbq.x = cb0; cbq.y = cb1; cbq.z = cb2; cbq.w = cb3;
        f16x8 Bconv = __builtin_bit_cast(f16x8, cbq);

        f32x4 z = {0.f, 0.f, 0.f, 0.f};
        f32x4 cv0 = __builtin_amdgcn_mfma_f32_16x16x32_f16(WA0, Bconv, z, 0, 0, 0);
        f32x4 cv1 = __builtin_amdgcn_mfma_f32_16x16x32_f16(WA1, Bconv, z, 0, 0, 0);

        // LN affine -> MLP B-frag (sigma-ordered)
        h2 lw2[4], lb2[4];
        if constexpr (PACKED) {
            uint4 A  = lnq[((size_t)lt * 64 + lane) * 2 + 0];
            uint4 Bv = lnq[((size_t)lt * 64 + lane) * 2 + 1];
            lw2[0] = bch2u(A.x);  lw2[1] = bch2u(A.y);
            lw2[2] = bch2u(A.z);  lw2[3] = bch2u(A.w);
            lb2[0] = bch2u(Bv.x); lb2[1] = bch2u(Bv.y);
            lb2[2] = bch2u(Bv.z); lb2[3] = bch2u(Bv.w);
        } else {
            #pragma unroll
            for (int p = 0; p < 4; ++p) {
                int ma = sigma_pair(gq, p), mb = ma + 1;
                float lwa = (ma < Mc) ? ln_w[(size_t)l * Mc + ma] : 0.f;
                float lwb = (mb < Mc) ? ln_w[(size_t)l * Mc + mb] : 0.f;
                float lba = (ma < Mc) ? ln_b[(size_t)l * Mc + ma] : ((ma == Mc) ? 1.f : 0.f);
                float lbb = (mb < Mc) ? ln_b[(size_t)l * Mc + mb] : ((mb == Mc) ? 1.f : 0.f);
                lw2[p] = pkh(lwa, lwb);
                lb2[p] = pkh(lba, lbb);
            }
        }
        unsigned Bu0, Bu1, Bu2, Bu3;
        {
            h2 dp, aw;
            dp = pkh(cv0[0], cv0[1]); aw = lw2[0] * rs2; Bu0 = bcu(dp * aw + (nm2 * aw + lb2[0]));
            dp = pkh(cv0[2], cv0[3]); aw = lw2[1] * rs2; Bu1 = bcu(dp * aw + (nm2 * aw + lb2[1]));
            dp = pkh(cv1[0], cv1[1]); aw = lw2[2] * rs2; Bu2 = bcu(dp * aw + (nm2 * aw + lb2[2]));
            dp = pkh(cv1[2], cv1[3]); aw = lw2[3] * rs2; Bu3 = bcu(dp * aw + (nm2 * aw + lb2[3]));
        }
        uint4 Bq; Bq.x = Bu0; Bq.y = Bu1; Bq.z = Bu2; Bq.w = Bu3;
        f16x8 Bfrag = __builtin_bit_cast(f16x8, Bq);

        f32x4 cf0 = __builtin_amdgcn_mfma_f32_16x16x32_f16(Afrag[0], Bfrag, z, 0, 0, 0);
        f32x4 cf1 = __builtin_amdgcn_mfma_f32_16x16x32_f16(Afrag[1], Bfrag, z, 0, 0, 0);
        f32x4 cf2 = __builtin_amdgcn_mfma_f32_16x16x32_f16(Afrag[2], Bfrag, z, 0, 0, 0);

        float acc = 0.f;
        acc = fmaf(gelu_f(cf0[0]), wbreg[0],  acc);
        acc = fmaf(gelu_f(cf0[1]), wbreg[1],  acc);
        acc = fmaf(gelu_f(cf0[2]), wbreg[2],  acc);
        acc = fmaf(gelu_f(cf0[3]), wbreg[3],  acc);
        acc = fmaf(gelu_f(cf1[0]), wbreg[4],  acc);
        acc = fmaf(gelu_f(cf1[1]), wbreg[5],  acc);
        acc = fmaf(gelu_f(cf1[2]), wbreg[6],  acc);
        acc = fmaf(gelu_f(cf1[3]), wbreg[7],  acc);
        acc = fmaf(gelu_f(cf2[0]), wbreg[8],  acc);
        acc = fmaf(gelu_f(cf2[1]), wbreg[9],  acc);
        acc = fmaf(gelu_f(cf2[2]), wbreg[10], acc);
        acc = fmaf(gelu_f(cf2[3]), wbreg[11], acc);

        acc += __shfl_xor(acc, 16);
        acc += __shfl_xor(acc, 32);

        if (lane < 16)
            out[(size_t)bc * Lc + l] = xs[9 + l] + acc + bbar;
    }
}

extern "C" void kernel_launch(void* const* d_in, const int* in_sizes, int n_in,
                              void* d_out, int out_size, void* d_ws, size_t ws_size,
                              hipStream_t stream) {
    const float* x      = (const float*)d_in[0];
    const float* orders = (const float*)d_in[1];
    const float* ln_w   = (const float*)d_in[2];
    const float* ln_b   = (const float*)d_in[3];
    const float* w1     = (const float*)d_in[4];
    const float* b1     = (const float*)d_in[5];
    const float* w2     = (const float*)d_in[6];
    const float* b2     = (const float*)d_in[7];
    float* out = (float*)d_out;

    const int nbc = in_sizes[0] / Lc;   // B*C = 1472
    if (ws_size >= WS_NEED) {
        uint4* lnT = (uint4*)d_ws;
        repack_ln4<<<(NTILE * 64 + 255) / 256, 256, 0, stream>>>(ln_w, ln_b, lnT);
        frac4<true><<<nbc, NT, 0, stream>>>(x, orders, ln_w, ln_b, w1, b1, w2, b2,
                                            (const uint4*)lnT, out);
    } else {
        frac4<false><<<nbc, NT, 0, stream>>>(x, orders, ln_w, ln_b, w1, b1, w2, b2,
                                             nullptr, out);
    }
}